// Round 2
// baseline (8771.070 us; speedup 1.0000x reference)
//
#include <hip/hip_runtime.h>

#define DD 128   // input feature dim D
#define HH 256   // hidden dim H
#define OO 128   // output dim O

typedef unsigned short bf16_t;

__device__ __forceinline__ float bf2f(bf16_t u) {
  union { unsigned int i; float f; } v; v.i = ((unsigned int)u) << 16; return v.f;
}
__device__ __forceinline__ bf16_t f2bf(float f) {
  union { float f; unsigned int i; } v; v.f = f;
  unsigned int r = v.i + 0x7FFFu + ((v.i >> 16) & 1u);  // round-to-nearest-even
  return (bf16_t)(r >> 16);
}

// ---------------------------------------------------------------------------
__global__ void probe_k(float* __restrict__ out, int n, float v) {
  int i = blockIdx.x * blockDim.x + threadIdx.x;
  if (i < n) out[i] = v;
}

__global__ void count_edges_k(const int* __restrict__ src, const int* __restrict__ dst,
                              float* __restrict__ cu, float* __restrict__ ci, int E) {
  int i = blockIdx.x * blockDim.x + threadIdx.x;
  if (i < E) {
    atomicAdd(cu + src[i], 1.0f);
    atomicAdd(ci + dst[i], 1.0f);
  }
}

__global__ void recip_k(float* __restrict__ c, int n) {
  int i = blockIdx.x * blockDim.x + threadIdx.x;
  if (i < n) c[i] = 1.0f / fmaxf(c[i], 1.0f);
}

// ---------------------------------------------------------------------------
// Layer-1 bidirectional scatter (f32 sources): agg_d[dst]+=xs[src], agg_s[src]+=xd[dst]
__global__ void scatter1_k(const int* __restrict__ src, const int* __restrict__ dst,
                           const float* __restrict__ xs, const float* __restrict__ xd,
                           float* __restrict__ agg_d, float* __restrict__ agg_s, int E) {
  const int QP = DD / 4;  // 32
  long long idx = (long long)blockIdx.x * blockDim.x + threadIdx.x;
  int e = (int)(idx / QP);
  int q = ((int)(idx % QP)) * 4;
  if (e >= E) return;
  int s = src[e], d = dst[e];
  float4 a = *(const float4*)(xs + (size_t)s * DD + q);
  float* p = agg_d + (size_t)d * DD + q;
  atomicAdd(p + 0, a.x); atomicAdd(p + 1, a.y);
  atomicAdd(p + 2, a.z); atomicAdd(p + 3, a.w);
  float4 b = *(const float4*)(xd + (size_t)d * DD + q);
  float* p2 = agg_s + (size_t)s * DD + q;
  atomicAdd(p2 + 0, b.x); atomicAdd(p2 + 1, b.y);
  atomicAdd(p2 + 2, b.z); atomicAdd(p2 + 3, b.w);
}

// Layer-2 single-direction scatter from bf16 source: dst[to] += src[from]
__global__ void scatter2_k(const int* __restrict__ from_idx, const int* __restrict__ to_idx,
                           const bf16_t* __restrict__ src, float* __restrict__ dst, int E) {
  long long idx = (long long)blockIdx.x * blockDim.x + threadIdx.x;
  int e = (int)(idx >> 6);                 // HH/4 = 64 quads per edge
  int q = ((int)(idx & 63)) * 4;
  if (e >= E) return;
  int s = from_idx[e], d = to_idx[e];
  short4 a = *(const short4*)(src + (size_t)s * HH + q);
  float* p = dst + (size_t)d * HH + q;
  atomicAdd(p + 0, bf2f((bf16_t)a.x));
  atomicAdd(p + 1, bf2f((bf16_t)a.y));
  atomicAdd(p + 2, bf2f((bf16_t)a.z));
  atomicAdd(p + 3, bf2f((bf16_t)a.w));
}

// ---------------------------------------------------------------------------
// Dual GEMM: C_bf16 = act( (A1*rowscale) @ W1 + A2 @ W2 + bias )
// A1 f32 [M,K]; A2 f32 or bf16 [M,K]; W1,W2 f32 [K,N]; C bf16 [M,N].
// 64x64 tile / 256 threads / 4x4 per thread / BK=16.
#define BM 64
#define BN 64
#define BK 16

template<bool RELU, bool A2BF>
__global__ __launch_bounds__(256) void dualgemm_k(
    int M, int N, int K,
    const float* __restrict__ A1, const float* __restrict__ rs1,
    const float* __restrict__ W1,
    const void* __restrict__ A2v, const float* __restrict__ W2,
    const float* __restrict__ bias, bf16_t* __restrict__ C) {
  __shared__ float As[BM][BK + 1];
  __shared__ float Bs[BK][BN + 4];
  const int tid = threadIdx.x;
  const int tx = tid & 15, ty = tid >> 4;
  const int row0 = blockIdx.y * BM, col0 = blockIdx.x * BN;
  const int lr = tid >> 2;           // A row in tile (0..63)
  const int lk = (tid & 3) * 4;      // A k quad
  const int br = tid >> 4;           // B k row (0..15)
  const int bc = (tid & 15) * 4;     // B col quad

  float acc[4][4] = {{0.f}};

  for (int s = 0; s < 2; ++s) {
    const float* __restrict__ W = s ? W2 : W1;
    for (int k0 = 0; k0 < K; k0 += BK) {
      const int ar = row0 + lr;
      float4 av = make_float4(0.f, 0.f, 0.f, 0.f);
      float scale = 1.0f;
      if (ar < M) {
        if (s == 0) {
          av = *(const float4*)(A1 + (size_t)ar * K + k0 + lk);
          scale = rs1[ar];
        } else if (A2BF) {
          short4 t = *(const short4*)((const bf16_t*)A2v + (size_t)ar * K + k0 + lk);
          av = make_float4(bf2f((bf16_t)t.x), bf2f((bf16_t)t.y),
                           bf2f((bf16_t)t.z), bf2f((bf16_t)t.w));
        } else {
          av = *(const float4*)((const float*)A2v + (size_t)ar * K + k0 + lk);
        }
      }
      As[lr][lk + 0] = av.x * scale;
      As[lr][lk + 1] = av.y * scale;
      As[lr][lk + 2] = av.z * scale;
      As[lr][lk + 3] = av.w * scale;
      float4 bv = *(const float4*)(W + (size_t)(k0 + br) * N + col0 + bc);
      Bs[br][bc + 0] = bv.x;
      Bs[br][bc + 1] = bv.y;
      Bs[br][bc + 2] = bv.z;
      Bs[br][bc + 3] = bv.w;
      __syncthreads();
#pragma unroll
      for (int kk = 0; kk < BK; ++kk) {
        float a[4], b[4];
#pragma unroll
        for (int i = 0; i < 4; ++i) a[i] = As[ty * 4 + i][kk];
#pragma unroll
        for (int j = 0; j < 4; ++j) b[j] = Bs[kk][tx * 4 + j];
#pragma unroll
        for (int i = 0; i < 4; ++i)
#pragma unroll
          for (int j = 0; j < 4; ++j) acc[i][j] += a[i] * b[j];
      }
      __syncthreads();
    }
  }

#pragma unroll
  for (int i = 0; i < 4; ++i) {
    int r = row0 + ty * 4 + i;
    if (r < M) {
      ushort4 o;
      float v0 = acc[i][0] + bias[col0 + tx * 4 + 0];
      float v1 = acc[i][1] + bias[col0 + tx * 4 + 1];
      float v2 = acc[i][2] + bias[col0 + tx * 4 + 2];
      float v3 = acc[i][3] + bias[col0 + tx * 4 + 3];
      if (RELU) {
        v0 = fmaxf(v0, 0.f); v1 = fmaxf(v1, 0.f);
        v2 = fmaxf(v2, 0.f); v3 = fmaxf(v3, 0.f);
      }
      o.x = f2bf(v0); o.y = f2bf(v1); o.z = f2bf(v2); o.w = f2bf(v3);
      *(ushort4*)(C + (size_t)r * N + col0 + tx * 4) = o;
    }
  }
}

// ---------------------------------------------------------------------------
// Decode: out[l] = dot(z_user[ls[l]], z_item[ld[l]]) over O=128 (bf16 inputs).
__global__ void decode_k(const int* __restrict__ ls, const int* __restrict__ ld,
                         const bf16_t* __restrict__ zu, const bf16_t* __restrict__ zi,
                         float* __restrict__ out, int L) {
  int w = (int)(((long long)blockIdx.x * blockDim.x + threadIdx.x) >> 6);
  int lane = threadIdx.x & 63;
  if (w >= L) return;
  int su = ls[w], si = ld[w];
  ushort2 u = *(const ushort2*)(zu + (size_t)su * OO + lane * 2);
  ushort2 v = *(const ushort2*)(zi + (size_t)si * OO + lane * 2);
  float sum = bf2f(u.x) * bf2f(v.x) + bf2f(u.y) * bf2f(v.y);
#pragma unroll
  for (int off = 32; off; off >>= 1) sum += __shfl_xor(sum, off);
  if (lane == 0) out[w] = sum;
}

// ---------------------------------------------------------------------------
extern "C" void kernel_launch(void* const* d_in, const int* in_sizes, int n_in,
                              void* d_out, int out_size, void* d_ws, size_t ws_size,
                              hipStream_t stream) {
  const float* x_user = (const float*)d_in[0];
  const float* x_item = (const float*)d_in[1];
  const int* edge_src = (const int*)d_in[2];
  const int* edge_dst = (const int*)d_in[3];
  const int* lbl_src  = (const int*)d_in[4];
  const int* lbl_dst  = (const int*)d_in[5];
  const float* wl1_ui = (const float*)d_in[6];
  const float* wr1_ui = (const float*)d_in[7];
  const float* b1_ui  = (const float*)d_in[8];
  const float* wl1_iu = (const float*)d_in[9];
  const float* wr1_iu = (const float*)d_in[10];
  const float* b1_iu  = (const float*)d_in[11];
  const float* wl2_ui = (const float*)d_in[12];
  const float* wr2_ui = (const float*)d_in[13];
  const float* b2_ui  = (const float*)d_in[14];
  const float* wl2_iu = (const float*)d_in[15];
  const float* wr2_iu = (const float*)d_in[16];
  const float* b2_iu  = (const float*)d_in[17];

  const int NU = in_sizes[0] / DD;
  const int NI = in_sizes[1] / DD;
  const int E  = in_sizes[2];
  const int L  = in_sizes[4];

  // ---- workspace layout (bytes) ----
  // [cnt_i | cnt_u] [pool P: agg1 / agg_i2 / agg_u2 (overlaid) | z_item | z_user] [h_item | h_user]
  size_t cntB   = (size_t)(NI + NU) * 4;
  size_t Poff   = (cntB + 255) & ~(size_t)255;
  size_t aggMax = (size_t)NU * HH * 4;            // largest overlay occupant (102.4 MB)
  size_t ziB    = (size_t)NI * OO * 2;
  size_t zuB    = (size_t)NU * OO * 2;
  size_t poolB  = aggMax + ziB + zuB;
  size_t Hoff   = ((Poff + poolB) + 255) & ~(size_t)255;
  size_t hB     = (size_t)(NI + NU) * HH * 2;
  size_t need   = Hoff + hB;                      // ~218 MB

  float* out = (float*)d_out;
  if (ws_size < need) {
    // diagnostic: surface ws_size (in MB) as the output so absmax reveals it
    probe_k<<<(L + 255) / 256, 256, 0, stream>>>(out, L, (float)(ws_size >> 20));
    return;
  }

  char* base = (char*)d_ws;
  float* cnt_i  = (float*)base;                  // NI
  float* cnt_u  = cnt_i + NI;                    // NU
  float* P      = (float*)(base + Poff);
  float* agg_i  = P;                             // NI*DD (layer-1)
  float* agg_u  = agg_i + (size_t)NI * DD;       // NU*DD
  float* agg_i2 = P;                             // NI*HH (overlays dead agg1)
  float* agg_u2 = P;                             // NU*HH (overlays dead agg_i2)
  bf16_t* z_item = (bf16_t*)(base + Poff + aggMax);   // NI*OO
  bf16_t* z_user = z_item + (size_t)NI * OO;          // NU*OO
  bf16_t* h_item = (bf16_t*)(base + Hoff);            // NI*HH
  bf16_t* h_user = h_item + (size_t)NI * HH;          // NU*HH

  // ---- zero counts + layer-1 agg ----
  hipMemsetAsync(base, 0, cntB, stream);
  hipMemsetAsync(P, 0, (size_t)(NI + NU) * DD * 4, stream);

  // counts
  count_edges_k<<<(E + 255) / 256, 256, 0, stream>>>(edge_src, edge_dst, cnt_u, cnt_i, E);

  // layer-1 scatter
  {
    long long total = (long long)E * (DD / 4);
    scatter1_k<<<(int)((total + 255) / 256), 256, 0, stream>>>(
        edge_src, edge_dst, x_user, x_item, agg_i, agg_u, E);
  }
  recip_k<<<(NI + NU + 255) / 256, 256, 0, stream>>>(cnt_i, NI + NU);

  // layer-1 GEMMs -> h (bf16)
  {
    dim3 g(HH / BN, (NI + BM - 1) / BM);
    dualgemm_k<true, false><<<g, 256, 0, stream>>>(NI, HH, DD, agg_i, cnt_i, wl1_ui,
                                                   (const void*)x_item, wr1_ui, b1_ui, h_item);
    dim3 g2(HH / BN, (NU + BM - 1) / BM);
    dualgemm_k<true, false><<<g2, 256, 0, stream>>>(NU, HH, DD, agg_u, cnt_u, wl1_iu,
                                                    (const void*)x_user, wr1_iu, b1_iu, h_user);
  }

  // layer-2, item side: agg_i2[dst] += h_user[src]; z_item = gemm
  hipMemsetAsync(agg_i2, 0, (size_t)NI * HH * 4, stream);
  {
    long long total = (long long)E * (HH / 4);
    scatter2_k<<<(int)((total + 255) / 256), 256, 0, stream>>>(
        edge_src, edge_dst, h_user, agg_i2, E);
  }
  {
    dim3 g(OO / BN, (NI + BM - 1) / BM);
    dualgemm_k<false, true><<<g, 256, 0, stream>>>(NI, OO, HH, agg_i2, cnt_i, wl2_ui,
                                                   (const void*)h_item, wr2_ui, b2_ui, z_item);
  }

  // layer-2, user side: agg_u2[src] += h_item[dst]; z_user = gemm
  hipMemsetAsync(agg_u2, 0, (size_t)NU * HH * 4, stream);
  {
    long long total = (long long)E * (HH / 4);
    scatter2_k<<<(int)((total + 255) / 256), 256, 0, stream>>>(
        edge_dst, edge_src, h_item, agg_u2, E);
  }
  {
    dim3 g(OO / BN, (NU + BM - 1) / BM);
    dualgemm_k<false, true><<<g, 256, 0, stream>>>(NU, OO, HH, agg_u2, cnt_u, wl2_iu,
                                                   (const void*)h_user, wr2_iu, b2_iu, z_user);
  }

  // decode
  {
    long long total = (long long)L * 64;
    decode_k<<<(int)((total + 255) / 256), 256, 0, stream>>>(lbl_src, lbl_dst, z_user, z_item, out, L);
  }
}

// Round 3
// 1084.013 us; speedup vs baseline: 8.0913x; 8.0913x over previous
//
#include <hip/hip_runtime.h>

#define DD 128   // input feature dim D
#define HH 256   // hidden dim H
#define OO 128   // output dim O

typedef unsigned short bf16_t;

__device__ __forceinline__ float bf2f(bf16_t u) {
  union { unsigned int i; float f; } v; v.i = ((unsigned int)u) << 16; return v.f;
}
__device__ __forceinline__ bf16_t f2bf(float f) {
  union { float f; unsigned int i; } v; v.f = f;
  unsigned int r = v.i + 0x7FFFu + ((v.i >> 16) & 1u);  // RNE
  return (bf16_t)(r >> 16);
}

// ---------------------------------------------------------------------------
__global__ void probe_k(float* __restrict__ out, int n, float v) {
  int i = blockIdx.x * blockDim.x + threadIdx.x;
  if (i < n) out[i] = v;
}

// degree histogram (int atomics, E of them per side — cheap)
__global__ void degree_k(const int* __restrict__ src, const int* __restrict__ dst,
                         int* __restrict__ deg_u, int* __restrict__ deg_i, int E) {
  int i = blockIdx.x * blockDim.x + threadIdx.x;
  if (i < E) {
    atomicAdd(deg_u + src[i], 1);
    atomicAdd(deg_i + dst[i], 1);
  }
}

// ---- 3-kernel exclusive scan (chunk = 1024 elems = 256 thr x 4) ----
__global__ void scan1_k(const int* __restrict__ deg, int* __restrict__ excl,
                        int* __restrict__ part, int n) {
  __shared__ int lds[256];
  int b = blockIdx.x, tid = threadIdx.x;
  int base = b * 1024;
  int v[4]; int s = 0;
#pragma unroll
  for (int j = 0; j < 4; ++j) { int i = base + tid * 4 + j; v[j] = (i < n) ? deg[i] : 0; s += v[j]; }
  lds[tid] = s; __syncthreads();
  for (int off = 1; off < 256; off <<= 1) {
    int t = (tid >= off) ? lds[tid - off] : 0;
    __syncthreads(); lds[tid] += t; __syncthreads();
  }
  int run = lds[tid] - s;
  if (tid == 255) part[b] = lds[255];
#pragma unroll
  for (int j = 0; j < 4; ++j) { int i = base + tid * 4 + j; if (i < n) excl[i] = run; run += v[j]; }
}

__global__ void scan2_k(int* __restrict__ part, int nb) {  // nb <= 1024
  __shared__ int lds[1024];
  int tid = threadIdx.x;
  int v = (tid < nb) ? part[tid] : 0;
  lds[tid] = v; __syncthreads();
  for (int off = 1; off < 1024; off <<= 1) {
    int t = (tid >= off) ? lds[tid - off] : 0;
    __syncthreads(); lds[tid] += t; __syncthreads();
  }
  if (tid < nb) part[tid] = lds[tid] - v;
}

__global__ void scan3_k(int* __restrict__ row, const int* __restrict__ part, int n, int Etot) {
  int i = blockIdx.x * blockDim.x + threadIdx.x;
  if (i < n) row[i] += part[i >> 10];
  if (i == 0) row[n] = Etot;
}

__global__ void copy_cur_k(const int* __restrict__ row_i, const int* __restrict__ row_u,
                           int* __restrict__ cur_i, int* __restrict__ cur_u, int NI, int NU) {
  int i = blockIdx.x * blockDim.x + threadIdx.x;
  if (i < NI) cur_i[i] = row_i[i];
  else if (i < NI + NU) cur_u[i - NI] = row_u[i - NI];
}

// csr_i[slot of dst] = src ; csr_u[slot of src] = dst
__global__ void fill_csr_k(const int* __restrict__ src, const int* __restrict__ dst,
                           int* __restrict__ cur_i, int* __restrict__ cur_u,
                           int* __restrict__ csr_i, int* __restrict__ csr_u, int E) {
  int e = blockIdx.x * blockDim.x + threadIdx.x;
  if (e < E) {
    int s = src[e], d = dst[e];
    csr_i[atomicAdd(cur_i + d, 1)] = s;
    csr_u[atomicAdd(cur_u + s, 1)] = d;
  }
}

// ---------------------------------------------------------------------------
// Gather-mean: one wave per node; lanes cover D; output bf16 mean row.
template<int V, bool BF>
__device__ __forceinline__ void loadrow(float* t, const void* X, int idx, int lane) {
  if (BF) {
    const bf16_t* p = (const bf16_t*)X + (size_t)idx * (V * 64) + lane * V;
    if (V == 4) { ushort4 u = *(const ushort4*)p;
      t[0]=bf2f(u.x); t[1]=bf2f(u.y); t[2]=bf2f(u.z); t[3]=bf2f(u.w); }
    else { ushort2 u = *(const ushort2*)p; t[0]=bf2f(u.x); t[1]=bf2f(u.y); }
  } else {
    const float* p = (const float*)X + (size_t)idx * (V * 64) + lane * V;
    if (V == 2) { float2 u = *(const float2*)p; t[0]=u.x; t[1]=u.y; }
    else { float4 u = *(const float4*)p; t[0]=u.x; t[1]=u.y; t[2]=u.z; t[3]=u.w; }
  }
}

template<int D, bool SRCBF>
__global__ void gather_mean_k(const int* __restrict__ row, const int* __restrict__ csr,
                              const void* __restrict__ X, bf16_t* __restrict__ agg, int n) {
  constexpr int V = D / 64;
  int node = (int)(((long long)blockIdx.x * blockDim.x + threadIdx.x) >> 6);
  int lane = threadIdx.x & 63;
  if (node >= n) return;
  int beg = row[node], end = row[node + 1];
  float acc[V] = {};
  for (int j0 = beg; j0 < end; j0 += 64) {
    int my = (j0 + lane < end) ? csr[j0 + lane] : 0;
    int cnt = min(64, end - j0);
    int k = 0;
    for (; k + 4 <= cnt; k += 4) {
      int i0 = __shfl(my, k), i1 = __shfl(my, k + 1);
      int i2 = __shfl(my, k + 2), i3 = __shfl(my, k + 3);
      float t0[V], t1[V], t2[V], t3[V];
      loadrow<V, SRCBF>(t0, X, i0, lane);
      loadrow<V, SRCBF>(t1, X, i1, lane);
      loadrow<V, SRCBF>(t2, X, i2, lane);
      loadrow<V, SRCBF>(t3, X, i3, lane);
#pragma unroll
      for (int v = 0; v < V; ++v) acc[v] += (t0[v] + t1[v]) + (t2[v] + t3[v]);
    }
    for (; k < cnt; ++k) {
      int i0 = __shfl(my, k);
      float t0[V];
      loadrow<V, SRCBF>(t0, X, i0, lane);
#pragma unroll
      for (int v = 0; v < V; ++v) acc[v] += t0[v];
    }
  }
  float inv = (end > beg) ? 1.0f / (float)(end - beg) : 0.0f;
  bf16_t* po = agg + (size_t)node * D + lane * V;
  if (V == 4) {
    ushort4 o; o.x=f2bf(acc[0]*inv); o.y=f2bf(acc[1]*inv); o.z=f2bf(acc[2]*inv); o.w=f2bf(acc[3]*inv);
    *(ushort4*)po = o;
  } else {
    ushort2 o; o.x=f2bf(acc[0]*inv); o.y=f2bf(acc[1]*inv);
    *(ushort2*)po = o;
  }
}

// ---------------------------------------------------------------------------
// Dual GEMM: C_bf16 = act( A1 @ W1 + A2 @ W2 + bias )
// A1 bf16 [M,K]; A2 f32 or bf16 [M,K]; W1,W2 f32 [K,N]; C bf16 [M,N].
#define BM 64
#define BN 64
#define BK 16

template<bool RELU, bool A2BF>
__global__ __launch_bounds__(256) void dualgemm_k(
    int M, int N, int K,
    const bf16_t* __restrict__ A1, const float* __restrict__ W1,
    const void* __restrict__ A2v, const float* __restrict__ W2,
    const float* __restrict__ bias, bf16_t* __restrict__ C) {
  __shared__ float As[BM][BK + 1];
  __shared__ float Bs[BK][BN + 4];
  const int tid = threadIdx.x;
  const int tx = tid & 15, ty = tid >> 4;
  const int row0 = blockIdx.y * BM, col0 = blockIdx.x * BN;
  const int lr = tid >> 2;           // A row in tile (0..63)
  const int lk = (tid & 3) * 4;      // A k quad
  const int br = tid >> 4;           // B k row (0..15)
  const int bc = (tid & 15) * 4;     // B col quad

  float acc[4][4] = {{0.f}};

  for (int s = 0; s < 2; ++s) {
    const float* __restrict__ W = s ? W2 : W1;
    for (int k0 = 0; k0 < K; k0 += BK) {
      const int ar = row0 + lr;
      float4 av = make_float4(0.f, 0.f, 0.f, 0.f);
      if (ar < M) {
        if (s == 0) {
          short4 t = *(const short4*)(A1 + (size_t)ar * K + k0 + lk);
          av = make_float4(bf2f((bf16_t)t.x), bf2f((bf16_t)t.y),
                           bf2f((bf16_t)t.z), bf2f((bf16_t)t.w));
        } else if (A2BF) {
          short4 t = *(const short4*)((const bf16_t*)A2v + (size_t)ar * K + k0 + lk);
          av = make_float4(bf2f((bf16_t)t.x), bf2f((bf16_t)t.y),
                           bf2f((bf16_t)t.z), bf2f((bf16_t)t.w));
        } else {
          av = *(const float4*)((const float*)A2v + (size_t)ar * K + k0 + lk);
        }
      }
      As[lr][lk + 0] = av.x;
      As[lr][lk + 1] = av.y;
      As[lr][lk + 2] = av.z;
      As[lr][lk + 3] = av.w;
      float4 bv = *(const float4*)(W + (size_t)(k0 + br) * N + col0 + bc);
      Bs[br][bc + 0] = bv.x;
      Bs[br][bc + 1] = bv.y;
      Bs[br][bc + 2] = bv.z;
      Bs[br][bc + 3] = bv.w;
      __syncthreads();
#pragma unroll
      for (int kk = 0; kk < BK; ++kk) {
        float a[4], b[4];
#pragma unroll
        for (int i = 0; i < 4; ++i) a[i] = As[ty * 4 + i][kk];
#pragma unroll
        for (int j = 0; j < 4; ++j) b[j] = Bs[kk][tx * 4 + j];
#pragma unroll
        for (int i = 0; i < 4; ++i)
#pragma unroll
          for (int j = 0; j < 4; ++j) acc[i][j] += a[i] * b[j];
      }
      __syncthreads();
    }
  }

#pragma unroll
  for (int i = 0; i < 4; ++i) {
    int r = row0 + ty * 4 + i;
    if (r < M) {
      float v0 = acc[i][0] + bias[col0 + tx * 4 + 0];
      float v1 = acc[i][1] + bias[col0 + tx * 4 + 1];
      float v2 = acc[i][2] + bias[col0 + tx * 4 + 2];
      float v3 = acc[i][3] + bias[col0 + tx * 4 + 3];
      if (RELU) {
        v0 = fmaxf(v0, 0.f); v1 = fmaxf(v1, 0.f);
        v2 = fmaxf(v2, 0.f); v3 = fmaxf(v3, 0.f);
      }
      ushort4 o; o.x = f2bf(v0); o.y = f2bf(v1); o.z = f2bf(v2); o.w = f2bf(v3);
      *(ushort4*)(C + (size_t)r * N + col0 + tx * 4) = o;
    }
  }
}

// ---------------------------------------------------------------------------
__global__ void decode_k(const int* __restrict__ ls, const int* __restrict__ ld,
                         const bf16_t* __restrict__ zu, const bf16_t* __restrict__ zi,
                         float* __restrict__ out, int L) {
  int w = (int)(((long long)blockIdx.x * blockDim.x + threadIdx.x) >> 6);
  int lane = threadIdx.x & 63;
  if (w >= L) return;
  int su = ls[w], si = ld[w];
  ushort2 u = *(const ushort2*)(zu + (size_t)su * OO + lane * 2);
  ushort2 v = *(const ushort2*)(zi + (size_t)si * OO + lane * 2);
  float sum = bf2f(u.x) * bf2f(v.x) + bf2f(u.y) * bf2f(v.y);
#pragma unroll
  for (int off = 32; off; off >>= 1) sum += __shfl_xor(sum, off);
  if (lane == 0) out[w] = sum;
}

// ---------------------------------------------------------------------------
extern "C" void kernel_launch(void* const* d_in, const int* in_sizes, int n_in,
                              void* d_out, int out_size, void* d_ws, size_t ws_size,
                              hipStream_t stream) {
  const float* x_user = (const float*)d_in[0];
  const float* x_item = (const float*)d_in[1];
  const int* edge_src = (const int*)d_in[2];
  const int* edge_dst = (const int*)d_in[3];
  const int* lbl_src  = (const int*)d_in[4];
  const int* lbl_dst  = (const int*)d_in[5];
  const float* wl1_ui = (const float*)d_in[6];
  const float* wr1_ui = (const float*)d_in[7];
  const float* b1_ui  = (const float*)d_in[8];
  const float* wl1_iu = (const float*)d_in[9];
  const float* wr1_iu = (const float*)d_in[10];
  const float* b1_iu  = (const float*)d_in[11];
  const float* wl2_ui = (const float*)d_in[12];
  const float* wr2_ui = (const float*)d_in[13];
  const float* b2_ui  = (const float*)d_in[14];
  const float* wl2_iu = (const float*)d_in[15];
  const float* wr2_iu = (const float*)d_in[16];
  const float* b2_iu  = (const float*)d_in[17];

  const int NU = in_sizes[0] / DD;
  const int NI = in_sizes[1] / DD;
  const int E  = in_sizes[2];
  const int L  = in_sizes[4];

  const int nb_i = (NI + 1023) / 1024, nb_u = (NU + 1023) / 1024;

  // ---- workspace layout ----
  size_t off = 0;
  auto take = [&](size_t bytes) { size_t o = off; off = (off + bytes + 255) & ~(size_t)255; return o; };
  char* base = (char*)d_ws;
  int* deg_i = (int*)(base + take((size_t)NI * 4));
  int* deg_u = (int*)(base + take((size_t)NU * 4));          // deg_i,deg_u zeroed together below
  size_t degB = (size_t)((char*)(deg_u + NU) - (char*)deg_i);
  int* row_i = (int*)(base + take((size_t)(NI + 1) * 4));
  int* row_u = (int*)(base + take((size_t)(NU + 1) * 4));
  int* cur_i = (int*)(base + take((size_t)NI * 4));
  int* cur_u = (int*)(base + take((size_t)NU * 4));
  int* part_i = (int*)(base + take((size_t)nb_i * 4));
  int* part_u = (int*)(base + take((size_t)nb_u * 4));
  int* csr_i = (int*)(base + take((size_t)E * 4));
  int* csr_u = (int*)(base + take((size_t)E * 4));
  // agg pool (overlaid between layers): layer2 is the larger (bf16, (NI+NU)*HH)
  size_t poolOff = take((size_t)(NI + NU) * HH * 2);
  bf16_t* agg_i  = (bf16_t*)(base + poolOff);                 // NI*DD (layer 1)
  bf16_t* agg_u  = agg_i + (size_t)NI * DD;
  bf16_t* agg_i2 = (bf16_t*)(base + poolOff);                 // NI*HH (layer 2, overlays)
  bf16_t* agg_u2 = agg_i2 + (size_t)NI * HH;
  bf16_t* h_item = (bf16_t*)(base + take((size_t)(NI + NU) * HH * 2));
  bf16_t* h_user = h_item + (size_t)NI * HH;
  bf16_t* z_item = (bf16_t*)(base + take((size_t)(NI + NU) * OO * 2));
  bf16_t* z_user = z_item + (size_t)NI * OO;
  size_t need = off;

  float* out = (float*)d_out;
  if (ws_size < need) {  // diagnostic: surface ws_size in MB via absmax
    probe_k<<<(L + 255) / 256, 256, 0, stream>>>(out, L, (float)(ws_size >> 20));
    return;
  }

  // ---- build CSR ----
  hipMemsetAsync(deg_i, 0, degB, stream);
  degree_k<<<(E + 255) / 256, 256, 0, stream>>>(edge_src, edge_dst, deg_u, deg_i, E);
  scan1_k<<<nb_i, 256, 0, stream>>>(deg_i, row_i, part_i, NI);
  scan1_k<<<nb_u, 256, 0, stream>>>(deg_u, row_u, part_u, NU);
  scan2_k<<<1, 1024, 0, stream>>>(part_i, nb_i);
  scan2_k<<<1, 1024, 0, stream>>>(part_u, nb_u);
  scan3_k<<<(NI + 255) / 256, 256, 0, stream>>>(row_i, part_i, NI, E);
  scan3_k<<<(NU + 255) / 256, 256, 0, stream>>>(row_u, part_u, NU, E);
  copy_cur_k<<<(NI + NU + 255) / 256, 256, 0, stream>>>(row_i, row_u, cur_i, cur_u, NI, NU);
  fill_csr_k<<<(E + 255) / 256, 256, 0, stream>>>(edge_src, edge_dst, cur_i, cur_u, csr_i, csr_u, E);

  // ---- layer 1: gather-mean + dual GEMM ----
  gather_mean_k<DD, false><<<(NI * 64 + 255) / 256, 256, 0, stream>>>(row_i, csr_i, x_user, agg_i, NI);
  gather_mean_k<DD, false><<<(NU * 64 + 255) / 256, 256, 0, stream>>>(row_u, csr_u, x_item, agg_u, NU);
  {
    dim3 g(HH / BN, (NI + BM - 1) / BM);
    dualgemm_k<true, false><<<g, 256, 0, stream>>>(NI, HH, DD, agg_i, wl1_ui,
                                                   (const void*)x_item, wr1_ui, b1_ui, h_item);
    dim3 g2(HH / BN, (NU + BM - 1) / BM);
    dualgemm_k<true, false><<<g2, 256, 0, stream>>>(NU, HH, DD, agg_u, wl1_iu,
                                                    (const void*)x_user, wr1_iu, b1_iu, h_user);
  }

  // ---- layer 2: gather-mean (from bf16 h) + dual GEMM ----
  gather_mean_k<HH, true><<<(NI * 64 + 255) / 256, 256, 0, stream>>>(row_i, csr_i, h_user, agg_i2, NI);
  gather_mean_k<HH, true><<<(NU * 64 + 255) / 256, 256, 0, stream>>>(row_u, csr_u, h_item, agg_u2, NU);
  {
    dim3 g(OO / BN, (NI + BM - 1) / BM);
    dualgemm_k<false, true><<<g, 256, 0, stream>>>(NI, OO, HH, agg_i2, wl2_ui,
                                                   (const void*)h_item, wr2_ui, b2_ui, z_item);
    dim3 g2(OO / BN, (NU + BM - 1) / BM);
    dualgemm_k<false, true><<<g2, 256, 0, stream>>>(NU, OO, HH, agg_u2, wl2_iu,
                                                    (const void*)h_user, wr2_iu, b2_iu, z_user);
  }

  // ---- decode ----
  decode_k<<<(int)(((long long)L * 64 + 255) / 256), 256, 0, stream>>>(lbl_src, lbl_dst, z_user, z_item, out, L);
}

// Round 4
// 622.427 us; speedup vs baseline: 14.0917x; 1.7416x over previous
//
#include <hip/hip_runtime.h>

#define DD 128   // input feature dim D
#define HH 256   // hidden dim H
#define OO 128   // output dim O

typedef unsigned short bf16_t;
typedef short bf16x8 __attribute__((ext_vector_type(8)));   // 8 bf16 = 4 VGPRs
typedef float f32x4 __attribute__((ext_vector_type(4)));

__device__ __forceinline__ float bf2f(bf16_t u) {
  union { unsigned int i; float f; } v; v.i = ((unsigned int)u) << 16; return v.f;
}
__device__ __forceinline__ bf16_t f2bf(float f) {
  union { float f; unsigned int i; } v; v.f = f;
  unsigned int r = v.i + 0x7FFFu + ((v.i >> 16) & 1u);  // RNE
  return (bf16_t)(r >> 16);
}

// ---------------------------------------------------------------------------
__global__ void probe_k(float* __restrict__ out, int n, float v) {
  int i = blockIdx.x * blockDim.x + threadIdx.x;
  if (i < n) out[i] = v;
}

// ---------------- CSR build ----------------
__global__ void degree_k(const int* __restrict__ src, const int* __restrict__ dst,
                         int* __restrict__ deg_u, int* __restrict__ deg_i, int E) {
  int i = blockIdx.x * blockDim.x + threadIdx.x;
  if (i < E) {
    atomicAdd(deg_u + src[i], 1);
    atomicAdd(deg_i + dst[i], 1);
  }
}

__global__ void scan1_k(const int* __restrict__ deg, int* __restrict__ excl,
                        int* __restrict__ part, int n) {
  __shared__ int lds[256];
  int b = blockIdx.x, tid = threadIdx.x;
  int base = b * 1024;
  int v[4]; int s = 0;
#pragma unroll
  for (int j = 0; j < 4; ++j) { int i = base + tid * 4 + j; v[j] = (i < n) ? deg[i] : 0; s += v[j]; }
  lds[tid] = s; __syncthreads();
  for (int off = 1; off < 256; off <<= 1) {
    int t = (tid >= off) ? lds[tid - off] : 0;
    __syncthreads(); lds[tid] += t; __syncthreads();
  }
  int run = lds[tid] - s;
  if (tid == 255) part[b] = lds[255];
#pragma unroll
  for (int j = 0; j < 4; ++j) { int i = base + tid * 4 + j; if (i < n) excl[i] = run; run += v[j]; }
}

__global__ void scan2_k(int* __restrict__ part, int nb) {  // nb <= 1024
  __shared__ int lds[1024];
  int tid = threadIdx.x;
  int v = (tid < nb) ? part[tid] : 0;
  lds[tid] = v; __syncthreads();
  for (int off = 1; off < 1024; off <<= 1) {
    int t = (tid >= off) ? lds[tid - off] : 0;
    __syncthreads(); lds[tid] += t; __syncthreads();
  }
  if (tid < nb) part[tid] = lds[tid] - v;
}

__global__ void scan3_k(int* __restrict__ row, const int* __restrict__ part, int n, int Etot) {
  int i = blockIdx.x * blockDim.x + threadIdx.x;
  if (i < n) row[i] += part[i >> 10];
  if (i == 0) row[n] = Etot;
}

__global__ void copy_cur_k(const int* __restrict__ row_i, const int* __restrict__ row_u,
                           int* __restrict__ cur_i, int* __restrict__ cur_u, int NI, int NU) {
  int i = blockIdx.x * blockDim.x + threadIdx.x;
  if (i < NI) cur_i[i] = row_i[i];
  else if (i < NI + NU) cur_u[i - NI] = row_u[i - NI];
}

__global__ void fill_csr_k(const int* __restrict__ src, const int* __restrict__ dst,
                           int* __restrict__ cur_i, int* __restrict__ cur_u,
                           int* __restrict__ csr_i, int* __restrict__ csr_u, int E) {
  int e = blockIdx.x * blockDim.x + threadIdx.x;
  if (e < E) {
    int s = src[e], d = dst[e];
    csr_i[atomicAdd(cur_i + d, 1)] = s;
    csr_u[atomicAdd(cur_u + s, 1)] = d;
  }
}

// ---------------- dtype prep ----------------
__global__ void cvt_bf16_k(const float* __restrict__ in, bf16_t* __restrict__ out, int n4) {
  int i = blockIdx.x * blockDim.x + threadIdx.x;
  if (i < n4) {
    float4 v = ((const float4*)in)[i];
    ushort4 o; o.x = f2bf(v.x); o.y = f2bf(v.y); o.z = f2bf(v.z); o.w = f2bf(v.w);
    ((ushort4*)out)[i] = o;
  }
}

// transpose-convert: in f32 [K,N] row-major -> out bf16 [N,K] row-major
__global__ void twconv_k(const float* __restrict__ in, bf16_t* __restrict__ out, int K, int N) {
  __shared__ float t[32][33];
  int bx = blockIdx.x * 32, by = blockIdx.y * 32;
  int tx = threadIdx.x & 31, ty = threadIdx.x >> 5;  // 32x8
#pragma unroll
  for (int j = 0; j < 32; j += 8)
    t[ty + j][tx] = in[(size_t)(by + ty + j) * N + bx + tx];
  __syncthreads();
#pragma unroll
  for (int j = 0; j < 32; j += 8)
    out[(size_t)(bx + ty + j) * K + by + tx] = f2bf(t[tx][ty + j]);
}

// ---------------- gather-mean (bf16 source, bf16 out) ----------------
template<int V>
__device__ __forceinline__ void loadrow(float* t, const bf16_t* X, int idx, int lane) {
  const bf16_t* p = X + (size_t)idx * (V * 64) + lane * V;
  if (V == 4) {
    ushort4 u = *(const ushort4*)p;
    t[0] = bf2f(u.x); t[1] = bf2f(u.y); t[2] = bf2f(u.z); t[3] = bf2f(u.w);
  } else {
    ushort2 u = *(const ushort2*)p; t[0] = bf2f(u.x); t[1] = bf2f(u.y);
  }
}

template<int D>
__global__ void gather_mean_k(const int* __restrict__ row, const int* __restrict__ csr,
                              const bf16_t* __restrict__ X, bf16_t* __restrict__ agg, int n) {
  constexpr int V = D / 64;
  int node = (int)(((long long)blockIdx.x * blockDim.x + threadIdx.x) >> 6);
  int lane = threadIdx.x & 63;
  if (node >= n) return;
  int beg = row[node], end = row[node + 1];
  float acc[V] = {};
  for (int j0 = beg; j0 < end; j0 += 64) {
    int my = (j0 + lane < end) ? csr[j0 + lane] : 0;
    int cnt = min(64, end - j0);
    int k = 0;
    for (; k + 4 <= cnt; k += 4) {
      int i0 = __shfl(my, k), i1 = __shfl(my, k + 1);
      int i2 = __shfl(my, k + 2), i3 = __shfl(my, k + 3);
      float t0[V], t1[V], t2[V], t3[V];
      loadrow<V>(t0, X, i0, lane);
      loadrow<V>(t1, X, i1, lane);
      loadrow<V>(t2, X, i2, lane);
      loadrow<V>(t3, X, i3, lane);
#pragma unroll
      for (int v = 0; v < V; ++v) acc[v] += (t0[v] + t1[v]) + (t2[v] + t3[v]);
    }
    for (; k < cnt; ++k) {
      int i0 = __shfl(my, k);
      float t0[V];
      loadrow<V>(t0, X, i0, lane);
#pragma unroll
      for (int v = 0; v < V; ++v) acc[v] += t0[v];
    }
  }
  float inv = (end > beg) ? 1.0f / (float)(end - beg) : 0.0f;
  bf16_t* po = agg + (size_t)node * D + lane * V;
  if (V == 4) {
    ushort4 o; o.x = f2bf(acc[0] * inv); o.y = f2bf(acc[1] * inv);
    o.z = f2bf(acc[2] * inv); o.w = f2bf(acc[3] * inv);
    *(ushort4*)po = o;
  } else {
    ushort2 o; o.x = f2bf(acc[0] * inv); o.y = f2bf(acc[1] * inv);
    *(ushort2*)po = o;
  }
}

// ---------------- MFMA dual GEMM ----------------
// C_bf16[M,N] = act( A1 @ W1 + A2 @ W2 + bias ),  A* bf16 [M,K] row-major,
// W*t bf16 [N,K] row-major (pre-transposed weights). N%128==0, K%32==0.
// 128x128 tile, 4 waves (2x2 of 64x64), BK=32, global_load_lds staging.
template<bool RELU>
__global__ __launch_bounds__(256) void mfma_dualgemm_k(
    int M, int N, int K,
    const bf16_t* __restrict__ A1, const bf16_t* __restrict__ A2,
    const bf16_t* __restrict__ W1t, const bf16_t* __restrict__ W2t,
    const float* __restrict__ bias, bf16_t* __restrict__ C) {
  __shared__ __align__(16) bf16_t Als[128 * 32];  // [row][k] 64B rows
  __shared__ __align__(16) bf16_t Bls[128 * 32];  // [col][k]
  const int tid = threadIdx.x;
  const int wave = tid >> 6, lane = tid & 63;
  const int wr = wave >> 1, wc = wave & 1;
  const size_t row0 = (size_t)blockIdx.y * 128;
  const int col0 = blockIdx.x * 128;

  f32x4 acc[4][4] = {};

  const int fbase = wave * 2048 + lane * 16;  // byte offset of this lane's 16B slot

#pragma unroll 2
  for (int s = 0; s < 2; ++s) {
    const bf16_t* __restrict__ Ap = s ? A2 : A1;
    const bf16_t* __restrict__ Wp = s ? W2t : W1t;
    for (int k0 = 0; k0 < K; k0 += 32) {
#pragma unroll
      for (int seg = 0; seg < 2; ++seg) {
        const int f = fbase + seg * 1024;
        const int r = f >> 6;              // tile row/col 0..127
        const int ke = (f & 63) >> 1;      // element offset within 32-elem k-slice
        size_t ar = row0 + r; if (ar >= (size_t)M) ar = M - 1;
        __builtin_amdgcn_global_load_lds(
            (const __attribute__((address_space(1))) void*)(Ap + ar * K + k0 + ke),
            (__attribute__((address_space(3))) void*)(Als + (f >> 1)), 16, 0, 0);
        __builtin_amdgcn_global_load_lds(
            (const __attribute__((address_space(1))) void*)(Wp + (size_t)(col0 + r) * K + k0 + ke),
            (__attribute__((address_space(3))) void*)(Bls + (f >> 1)), 16, 0, 0);
      }
      __syncthreads();  // drains vmcnt (compiler emits s_waitcnt vmcnt(0) before barrier)
      const int aoff = (wr * 64 + (lane & 15)) * 32 + (lane >> 4) * 8;
      const int boff = (wc * 64 + (lane & 15)) * 32 + (lane >> 4) * 8;
      bf16x8 af[4], bf[4];
#pragma unroll
      for (int i = 0; i < 4; ++i) {
        af[i] = *(const bf16x8*)(Als + aoff + i * 16 * 32);
        bf[i] = *(const bf16x8*)(Bls + boff + i * 16 * 32);
      }
#pragma unroll
      for (int mi = 0; mi < 4; ++mi)
#pragma unroll
        for (int ni = 0; ni < 4; ++ni)
          acc[mi][ni] = __builtin_amdgcn_mfma_f32_16x16x32_bf16(af[mi], bf[ni], acc[mi][ni], 0, 0, 0);
      __syncthreads();
    }
  }

  // epilogue: C row = row0 + wr*64 + mi*16 + (lane>>4)*4 + j ; col = col0 + wc*64 + ni*16 + (lane&15)
  const int crow = wr * 64 + (lane >> 4) * 4;
  const int ccol = col0 + wc * 64 + (lane & 15);
#pragma unroll
  for (int mi = 0; mi < 4; ++mi) {
#pragma unroll
    for (int j = 0; j < 4; ++j) {
      size_t r = row0 + crow + mi * 16 + j;
      if (r < (size_t)M) {
#pragma unroll
        for (int ni = 0; ni < 4; ++ni) {
          float v = acc[mi][ni][j] + bias[ccol + ni * 16];
          if (RELU) v = fmaxf(v, 0.f);
          C[r * N + ccol + ni * 16] = f2bf(v);
        }
      }
    }
  }
}

// ---------------- decode ----------------
__global__ void decode_k(const int* __restrict__ ls, const int* __restrict__ ld,
                         const bf16_t* __restrict__ zu, const bf16_t* __restrict__ zi,
                         float* __restrict__ out, int L) {
  int w = (int)(((long long)blockIdx.x * blockDim.x + threadIdx.x) >> 6);
  int lane = threadIdx.x & 63;
  if (w >= L) return;
  int su = ls[w], si = ld[w];
  ushort2 u = *(const ushort2*)(zu + (size_t)su * OO + lane * 2);
  ushort2 v = *(const ushort2*)(zi + (size_t)si * OO + lane * 2);
  float sum = bf2f(u.x) * bf2f(v.x) + bf2f(u.y) * bf2f(v.y);
#pragma unroll
  for (int off = 32; off; off >>= 1) sum += __shfl_xor(sum, off);
  if (lane == 0) out[w] = sum;
}

// ---------------------------------------------------------------------------
extern "C" void kernel_launch(void* const* d_in, const int* in_sizes, int n_in,
                              void* d_out, int out_size, void* d_ws, size_t ws_size,
                              hipStream_t stream) {
  const float* x_user = (const float*)d_in[0];
  const float* x_item = (const float*)d_in[1];
  const int* edge_src = (const int*)d_in[2];
  const int* edge_dst = (const int*)d_in[3];
  const int* lbl_src  = (const int*)d_in[4];
  const int* lbl_dst  = (const int*)d_in[5];
  const float* W_raw[8] = {
    (const float*)d_in[6],  (const float*)d_in[7],   // wl1_ui, wr1_ui  [D,H]
    (const float*)d_in[9],  (const float*)d_in[10],  // wl1_iu, wr1_iu  [D,H]
    (const float*)d_in[12], (const float*)d_in[13],  // wl2_ui, wr2_ui  [H,O]
    (const float*)d_in[15], (const float*)d_in[16],  // wl2_iu, wr2_iu  [H,O]
  };
  const float* b1_ui = (const float*)d_in[8];
  const float* b1_iu = (const float*)d_in[11];
  const float* b2_ui = (const float*)d_in[14];
  const float* b2_iu = (const float*)d_in[17];

  const int NU = in_sizes[0] / DD;
  const int NI = in_sizes[1] / DD;
  const int E  = in_sizes[2];
  const int L  = in_sizes[4];
  const int nb_i = (NI + 1023) / 1024, nb_u = (NU + 1023) / 1024;

  // ---- workspace layout ----
  size_t off = 0;
  auto take = [&](size_t bytes) { size_t o = off; off = (off + bytes + 255) & ~(size_t)255; return o; };
  char* base = (char*)d_ws;
  int* deg_i = (int*)(base + take((size_t)NI * 4));
  int* deg_u = (int*)(base + take((size_t)NU * 4));
  size_t degB = (size_t)((char*)(deg_u + NU) - (char*)deg_i);
  int* row_i = (int*)(base + take((size_t)(NI + 1) * 4));
  int* row_u = (int*)(base + take((size_t)(NU + 1) * 4));
  int* cur_i = (int*)(base + take((size_t)NI * 4));
  int* cur_u = (int*)(base + take((size_t)NU * 4));
  int* part_i = (int*)(base + take((size_t)nb_i * 4));
  int* part_u = (int*)(base + take((size_t)nb_u * 4));
  int* csr_i = (int*)(base + take((size_t)E * 4));
  int* csr_u = (int*)(base + take((size_t)E * 4));
  // pool: (NI+NU)*HH bf16. Layer 1: agg_i|agg_u|xb_item|xb_user (exactly fills).
  // Layer 2: agg_i2|agg_u2 (overlays).
  bf16_t* pool = (bf16_t*)(base + take((size_t)(NI + NU) * HH * 2));
  bf16_t* agg_i   = pool;                              // NI*DD
  bf16_t* agg_u   = agg_i + (size_t)NI * DD;           // NU*DD
  bf16_t* xb_item = agg_u + (size_t)NU * DD;           // NI*DD
  bf16_t* xb_user = xb_item + (size_t)NI * DD;         // NU*DD
  bf16_t* agg_i2  = pool;                              // NI*HH
  bf16_t* agg_u2  = agg_i2 + (size_t)NI * HH;          // NU*HH
  bf16_t* h_item = (bf16_t*)(base + take((size_t)(NI + NU) * HH * 2));
  bf16_t* h_user = h_item + (size_t)NI * HH;
  bf16_t* z_item = (bf16_t*)(base + take((size_t)(NI + NU) * OO * 2));
  bf16_t* z_user = z_item + (size_t)NI * OO;
  bf16_t* Wt[8];
  for (int w = 0; w < 8; ++w) Wt[w] = (bf16_t*)(base + take((size_t)DD * HH * 2));
  size_t need = off;

  float* out = (float*)d_out;
  if (ws_size < need) {  // diagnostic: surface ws_size in MB via absmax
    probe_k<<<(L + 255) / 256, 256, 0, stream>>>(out, L, (float)(ws_size >> 20));
    return;
  }

  // ---- CSR build ----
  hipMemsetAsync(deg_i, 0, degB, stream);
  degree_k<<<(E + 255) / 256, 256, 0, stream>>>(edge_src, edge_dst, deg_u, deg_i, E);
  scan1_k<<<nb_i, 256, 0, stream>>>(deg_i, row_i, part_i, NI);
  scan1_k<<<nb_u, 256, 0, stream>>>(deg_u, row_u, part_u, NU);
  scan2_k<<<1, 1024, 0, stream>>>(part_i, nb_i);
  scan2_k<<<1, 1024, 0, stream>>>(part_u, nb_u);
  scan3_k<<<(NI + 255) / 256, 256, 0, stream>>>(row_i, part_i, NI, E);
  scan3_k<<<(NU + 255) / 256, 256, 0, stream>>>(row_u, part_u, NU, E);
  copy_cur_k<<<(NI + NU + 255) / 256, 256, 0, stream>>>(row_i, row_u, cur_i, cur_u, NI, NU);
  fill_csr_k<<<(E + 255) / 256, 256, 0, stream>>>(edge_src, edge_dst, cur_i, cur_u, csr_i, csr_u, E);

  // ---- dtype prep ----
  cvt_bf16_k<<<(NI * DD / 4 + 255) / 256, 256, 0, stream>>>(x_item, xb_item, NI * DD / 4);
  cvt_bf16_k<<<(NU * DD / 4 + 255) / 256, 256, 0, stream>>>(x_user, xb_user, NU * DD / 4);
  {
    dim3 g1(HH / 32, DD / 32);  // layer-1 weights [D,H] -> [H,D]
    for (int w = 0; w < 4; ++w) twconv_k<<<g1, 256, 0, stream>>>(W_raw[w], Wt[w], DD, HH);
    dim3 g2(OO / 32, HH / 32);  // layer-2 weights [H,O] -> [O,H]
    for (int w = 4; w < 8; ++w) twconv_k<<<g2, 256, 0, stream>>>(W_raw[w], Wt[w], HH, OO);
  }

  // ---- layer 1 ----
  gather_mean_k<DD><<<(NI * 64 + 255) / 256, 256, 0, stream>>>(row_i, csr_i, xb_user, agg_i, NI);
  gather_mean_k<DD><<<(NU * 64 + 255) / 256, 256, 0, stream>>>(row_u, csr_u, xb_item, agg_u, NU);
  {
    dim3 g(HH / 128, (NI + 127) / 128);
    mfma_dualgemm_k<true><<<g, 256, 0, stream>>>(NI, HH, DD, agg_i, xb_item, Wt[0], Wt[1], b1_ui, h_item);
    dim3 g2(HH / 128, (NU + 127) / 128);
    mfma_dualgemm_k<true><<<g2, 256, 0, stream>>>(NU, HH, DD, agg_u, xb_user, Wt[2], Wt[3], b1_iu, h_user);
  }

  // ---- layer 2 ----
  gather_mean_k<HH><<<(NI * 64 + 255) / 256, 256, 0, stream>>>(row_i, csr_i, h_user, agg_i2, NI);
  gather_mean_k<HH><<<(NU * 64 + 255) / 256, 256, 0, stream>>>(row_u, csr_u, h_item, agg_u2, NU);
  {
    dim3 g(OO / 128, (NI + 127) / 128);
    mfma_dualgemm_k<false><<<g, 256, 0, stream>>>(NI, OO, HH, agg_i2, h_item, Wt[4], Wt[5], b2_ui, z_item);
    dim3 g2(OO / 128, (NU + 127) / 128);
    mfma_dualgemm_k<false><<<g2, 256, 0, stream>>>(NU, OO, HH, agg_u2, h_user, Wt[6], Wt[7], b2_iu, z_user);
  }

  // ---- decode ----
  decode_k<<<(int)(((long long)L * 64 + 255) / 256), 256, 0, stream>>>(lbl_src, lbl_dst, z_user, z_item, out, L);
}

// Round 5
// 603.148 us; speedup vs baseline: 14.5421x; 1.0320x over previous
//
#include <hip/hip_runtime.h>

#define DD 128   // input feature dim D
#define HH 256   // hidden dim H
#define OO 128   // output dim O

typedef unsigned short bf16_t;
typedef short bf16x8 __attribute__((ext_vector_type(8)));   // 8 bf16 = 4 VGPRs
typedef float f32x4 __attribute__((ext_vector_type(4)));

__device__ __forceinline__ float bf2f(bf16_t u) {
  union { unsigned int i; float f; } v; v.i = ((unsigned int)u) << 16; return v.f;
}
__device__ __forceinline__ bf16_t f2bf(float f) {
  union { float f; unsigned int i; } v; v.f = f;
  unsigned int r = v.i + 0x7FFFu + ((v.i >> 16) & 1u);  // RNE
  return (bf16_t)(r >> 16);
}

// ---------------------------------------------------------------------------
__global__ void probe_k(float* __restrict__ out, int n, float v) {
  int i = blockIdx.x * blockDim.x + threadIdx.x;
  if (i < n) out[i] = v;
}

// ---------------- CSR build ----------------
__global__ void degree_k(const int* __restrict__ src, const int* __restrict__ dst,
                         int* __restrict__ deg_u, int* __restrict__ deg_i, int E) {
  int i = blockIdx.x * blockDim.x + threadIdx.x;
  if (i < E) {
    atomicAdd(deg_u + src[i], 1);
    atomicAdd(deg_i + dst[i], 1);
  }
}

__global__ void scan1_k(const int* __restrict__ deg, int* __restrict__ excl,
                        int* __restrict__ part, int n) {
  __shared__ int lds[256];
  int b = blockIdx.x, tid = threadIdx.x;
  int base = b * 1024;
  int v[4]; int s = 0;
#pragma unroll
  for (int j = 0; j < 4; ++j) { int i = base + tid * 4 + j; v[j] = (i < n) ? deg[i] : 0; s += v[j]; }
  lds[tid] = s; __syncthreads();
  for (int off = 1; off < 256; off <<= 1) {
    int t = (tid >= off) ? lds[tid - off] : 0;
    __syncthreads(); lds[tid] += t; __syncthreads();
  }
  int run = lds[tid] - s;
  if (tid == 255) part[b] = lds[255];
#pragma unroll
  for (int j = 0; j < 4; ++j) { int i = base + tid * 4 + j; if (i < n) excl[i] = run; run += v[j]; }
}

__global__ void scan2_k(int* __restrict__ part, int nb) {  // nb <= 1024
  __shared__ int lds[1024];
  int tid = threadIdx.x;
  int v = (tid < nb) ? part[tid] : 0;
  lds[tid] = v; __syncthreads();
  for (int off = 1; off < 1024; off <<= 1) {
    int t = (tid >= off) ? lds[tid - off] : 0;
    __syncthreads(); lds[tid] += t; __syncthreads();
  }
  if (tid < nb) part[tid] = lds[tid] - v;
}

__global__ void scan3_k(int* __restrict__ row, const int* __restrict__ part, int n, int Etot) {
  int i = blockIdx.x * blockDim.x + threadIdx.x;
  if (i < n) row[i] += part[i >> 10];
  if (i == 0) row[n] = Etot;
}

__global__ void copy_cur_k(const int* __restrict__ row_i, const int* __restrict__ row_u,
                           int* __restrict__ cur_i, int* __restrict__ cur_u, int NI, int NU) {
  int i = blockIdx.x * blockDim.x + threadIdx.x;
  if (i < NI) cur_i[i] = row_i[i];
  else if (i < NI + NU) cur_u[i - NI] = row_u[i - NI];
}

__global__ void fill_csr_k(const int* __restrict__ src, const int* __restrict__ dst,
                           int* __restrict__ cur_i, int* __restrict__ cur_u,
                           int* __restrict__ csr_i, int* __restrict__ csr_u, int E) {
  int e = blockIdx.x * blockDim.x + threadIdx.x;
  if (e < E) {
    int s = src[e], d = dst[e];
    csr_i[atomicAdd(cur_i + d, 1)] = s;
    csr_u[atomicAdd(cur_u + s, 1)] = d;
  }
}

// ---------------- dtype prep ----------------
__global__ void cvt_bf16_k(const float* __restrict__ in, bf16_t* __restrict__ out, int n4) {
  int i = blockIdx.x * blockDim.x + threadIdx.x;
  if (i < n4) {
    float4 v = ((const float4*)in)[i];
    ushort4 o; o.x = f2bf(v.x); o.y = f2bf(v.y); o.z = f2bf(v.z); o.w = f2bf(v.w);
    ((ushort4*)out)[i] = o;
  }
}

// transpose-convert: in f32 [K,N] row-major -> out bf16 [N,K] row-major
__global__ void twconv_k(const float* __restrict__ in, bf16_t* __restrict__ out, int K, int N) {
  __shared__ float t[32][33];
  int bx = blockIdx.x * 32, by = blockIdx.y * 32;
  int tx = threadIdx.x & 31, ty = threadIdx.x >> 5;  // 32x8
#pragma unroll
  for (int j = 0; j < 32; j += 8)
    t[ty + j][tx] = in[(size_t)(by + ty + j) * N + bx + tx];
  __syncthreads();
#pragma unroll
  for (int j = 0; j < 32; j += 8)
    out[(size_t)(bx + ty + j) * K + by + tx] = f2bf(t[tx][ty + j]);
}

// ---------------- gather-mean (bf16 source) ----------------
template<int V>
__device__ __forceinline__ void loadrow(float* t, const bf16_t* X, int idx, int lane) {
  const bf16_t* p = X + (size_t)idx * (V * 64) + lane * V;
  if (V == 4) {
    ushort4 u = *(const ushort4*)p;
    t[0] = bf2f(u.x); t[1] = bf2f(u.y); t[2] = bf2f(u.z); t[3] = bf2f(u.w);
  } else {
    ushort2 u = *(const ushort2*)p; t[0] = bf2f(u.x); t[1] = bf2f(u.y);
  }
}

// ADD=false: agg[node] = mean(X[nbrs]).  ADD=true: agg[node] += mean(X[nbrs]).
template<int D, bool ADD>
__global__ void gather_mean_k(const int* __restrict__ row, const int* __restrict__ csr,
                              const bf16_t* __restrict__ X, bf16_t* __restrict__ agg, int n) {
  constexpr int V = D / 64;
  int node = (int)(((long long)blockIdx.x * blockDim.x + threadIdx.x) >> 6);
  int lane = threadIdx.x & 63;
  if (node >= n) return;
  int beg = row[node], end = row[node + 1];
  float acc[V] = {};
  for (int j0 = beg; j0 < end; j0 += 64) {
    int my = (j0 + lane < end) ? csr[j0 + lane] : 0;
    int cnt = min(64, end - j0);
    int k = 0;
    for (; k + 4 <= cnt; k += 4) {
      int i0 = __shfl(my, k), i1 = __shfl(my, k + 1);
      int i2 = __shfl(my, k + 2), i3 = __shfl(my, k + 3);
      float t0[V], t1[V], t2[V], t3[V];
      loadrow<V>(t0, X, i0, lane);
      loadrow<V>(t1, X, i1, lane);
      loadrow<V>(t2, X, i2, lane);
      loadrow<V>(t3, X, i3, lane);
#pragma unroll
      for (int v = 0; v < V; ++v) acc[v] += (t0[v] + t1[v]) + (t2[v] + t3[v]);
    }
    for (; k < cnt; ++k) {
      int i0 = __shfl(my, k);
      float t0[V];
      loadrow<V>(t0, X, i0, lane);
#pragma unroll
      for (int v = 0; v < V; ++v) acc[v] += t0[v];
    }
  }
  float inv = (end > beg) ? 1.0f / (float)(end - beg) : 0.0f;
  bf16_t* po = agg + (size_t)node * D + lane * V;
  if (V == 4) {
    float b0 = 0, b1 = 0, b2 = 0, b3 = 0;
    if (ADD) { ushort4 z = *(const ushort4*)po; b0 = bf2f(z.x); b1 = bf2f(z.y); b2 = bf2f(z.z); b3 = bf2f(z.w); }
    ushort4 o; o.x = f2bf(acc[0] * inv + b0); o.y = f2bf(acc[1] * inv + b1);
    o.z = f2bf(acc[2] * inv + b2); o.w = f2bf(acc[3] * inv + b3);
    *(ushort4*)po = o;
  } else {
    float b0 = 0, b1 = 0;
    if (ADD) { ushort2 z = *(const ushort2*)po; b0 = bf2f(z.x); b1 = bf2f(z.y); }
    ushort2 o; o.x = f2bf(acc[0] * inv + b0); o.y = f2bf(acc[1] * inv + b1);
    *(ushort2*)po = o;
  }
}

// ---------------- MFMA GEMM (single or dual A-source) ----------------
// C_bf16[M,N] = act( A1 @ W1 [+ A2 @ W2] [+ bias] ), A* bf16 [M,K] row-major,
// W*t bf16 [N,K] row-major (pre-transposed). N%128==0, K%32==0.
// 128x128 tile, 4 waves (2x2 of 64x64), BK=32, global_load_lds staging.
template<bool RELU, bool DUAL, bool BIAS>
__global__ __launch_bounds__(256) void mfma_gemm_k(
    int M, int N, int K,
    const bf16_t* __restrict__ A1, const bf16_t* __restrict__ A2,
    const bf16_t* __restrict__ W1t, const bf16_t* __restrict__ W2t,
    const float* __restrict__ bias, bf16_t* __restrict__ C) {
  __shared__ __align__(16) bf16_t Als[128 * 32];  // [row][k] 64B rows
  __shared__ __align__(16) bf16_t Bls[128 * 32];  // [col][k]
  const int tid = threadIdx.x;
  const int wave = tid >> 6, lane = tid & 63;
  const int wr = wave >> 1, wc = wave & 1;
  const size_t row0 = (size_t)blockIdx.y * 128;
  const int col0 = blockIdx.x * 128;

  f32x4 acc[4][4] = {};

  const int fbase = wave * 2048 + lane * 16;  // byte offset of this lane's 16B slot

  for (int s = 0; s < (DUAL ? 2 : 1); ++s) {
    const bf16_t* __restrict__ Ap = s ? A2 : A1;
    const bf16_t* __restrict__ Wp = s ? W2t : W1t;
    for (int k0 = 0; k0 < K; k0 += 32) {
#pragma unroll
      for (int seg = 0; seg < 2; ++seg) {
        const int f = fbase + seg * 1024;
        const int r = f >> 6;              // tile row/col 0..127
        const int ke = (f & 63) >> 1;      // element offset within 32-elem k-slice
        size_t ar = row0 + r; if (ar >= (size_t)M) ar = M - 1;
        __builtin_amdgcn_global_load_lds(
            (const __attribute__((address_space(1))) void*)(Ap + ar * K + k0 + ke),
            (__attribute__((address_space(3))) void*)(Als + (f >> 1)), 16, 0, 0);
        __builtin_amdgcn_global_load_lds(
            (const __attribute__((address_space(1))) void*)(Wp + (size_t)(col0 + r) * K + k0 + ke),
            (__attribute__((address_space(3))) void*)(Bls + (f >> 1)), 16, 0, 0);
      }
      __syncthreads();
      const int aoff = (wr * 64 + (lane & 15)) * 32 + (lane >> 4) * 8;
      const int boff = (wc * 64 + (lane & 15)) * 32 + (lane >> 4) * 8;
      bf16x8 af[4], bfr[4];
#pragma unroll
      for (int i = 0; i < 4; ++i) {
        af[i] = *(const bf16x8*)(Als + aoff + i * 16 * 32);
        bfr[i] = *(const bf16x8*)(Bls + boff + i * 16 * 32);
      }
#pragma unroll
      for (int mi = 0; mi < 4; ++mi)
#pragma unroll
        for (int ni = 0; ni < 4; ++ni)
          acc[mi][ni] = __builtin_amdgcn_mfma_f32_16x16x32_bf16(af[mi], bfr[ni], acc[mi][ni], 0, 0, 0);
      __syncthreads();
    }
  }

  const int crow = wr * 64 + (lane >> 4) * 4;
  const int ccol = col0 + wc * 64 + (lane & 15);
#pragma unroll
  for (int mi = 0; mi < 4; ++mi) {
#pragma unroll
    for (int j = 0; j < 4; ++j) {
      size_t r = row0 + crow + mi * 16 + j;
      if (r < (size_t)M) {
#pragma unroll
        for (int ni = 0; ni < 4; ++ni) {
          float v = acc[mi][ni][j];
          if (BIAS) v += bias[ccol + ni * 16];
          if (RELU) v = fmaxf(v, 0.f);
          C[r * N + ccol + ni * 16] = f2bf(v);
        }
      }
    }
  }
}

// ---------------- decode ----------------
__global__ void decode_k(const int* __restrict__ ls, const int* __restrict__ ld,
                         const bf16_t* __restrict__ zu, const bf16_t* __restrict__ zi,
                         float* __restrict__ out, int L) {
  int w = (int)(((long long)blockIdx.x * blockDim.x + threadIdx.x) >> 6);
  int lane = threadIdx.x & 63;
  if (w >= L) return;
  int su = ls[w], si = ld[w];
  ushort2 u = *(const ushort2*)(zu + (size_t)su * OO + lane * 2);
  ushort2 v = *(const ushort2*)(zi + (size_t)si * OO + lane * 2);
  float sum = bf2f(u.x) * bf2f(v.x) + bf2f(u.y) * bf2f(v.y);
#pragma unroll
  for (int off = 32; off; off >>= 1) sum += __shfl_xor(sum, off);
  if (lane == 0) out[w] = sum;
}

// ---------------------------------------------------------------------------
extern "C" void kernel_launch(void* const* d_in, const int* in_sizes, int n_in,
                              void* d_out, int out_size, void* d_ws, size_t ws_size,
                              hipStream_t stream) {
  const float* x_user = (const float*)d_in[0];
  const float* x_item = (const float*)d_in[1];
  const int* edge_src = (const int*)d_in[2];
  const int* edge_dst = (const int*)d_in[3];
  const int* lbl_src  = (const int*)d_in[4];
  const int* lbl_dst  = (const int*)d_in[5];
  const float* W_raw[8] = {
    (const float*)d_in[6],  (const float*)d_in[7],   // wl1_ui, wr1_ui  [D,H]
    (const float*)d_in[9],  (const float*)d_in[10],  // wl1_iu, wr1_iu  [D,H]
    (const float*)d_in[12], (const float*)d_in[13],  // wl2_ui, wr2_ui  [H,O]
    (const float*)d_in[15], (const float*)d_in[16],  // wl2_iu, wr2_iu  [H,O]
  };
  const float* b1_ui = (const float*)d_in[8];
  const float* b1_iu = (const float*)d_in[11];
  const float* b2_ui = (const float*)d_in[14];
  const float* b2_iu = (const float*)d_in[17];

  const int NU = in_sizes[0] / DD;
  const int NI = in_sizes[1] / DD;
  const int E  = in_sizes[2];
  const int L  = in_sizes[4];
  const int nb_i = (NI + 1023) / 1024, nb_u = (NU + 1023) / 1024;

  // ---- workspace layout ----
  size_t off = 0;
  auto take = [&](size_t bytes) { size_t o = off; off = (off + bytes + 255) & ~(size_t)255; return o; };
  char* base = (char*)d_ws;
  int* deg_i = (int*)(base + take((size_t)NI * 4));
  int* deg_u = (int*)(base + take((size_t)NU * 4));
  size_t degB = (size_t)((char*)(deg_u + NU) - (char*)deg_i);
  int* row_i = (int*)(base + take((size_t)(NI + 1) * 4));
  int* row_u = (int*)(base + take((size_t)(NU + 1) * 4));
  int* cur_i = (int*)(base + take((size_t)NI * 4));
  int* cur_u = (int*)(base + take((size_t)NU * 4));
  int* part_i = (int*)(base + take((size_t)nb_i * 4));
  int* part_u = (int*)(base + take((size_t)nb_u * 4));
  int* csr_i = (int*)(base + take((size_t)E * 4));
  int* csr_u = (int*)(base + take((size_t)E * 4));
  // pool: (NI+NU)*HH bf16.
  //  layer 1: agg_i|agg_u|xb_item|xb_user (exactly fills)
  //  layer 2: t_user|t_item (overlays, all layer-1 tenants dead)
  bf16_t* pool = (bf16_t*)(base + take((size_t)(NI + NU) * HH * 2));
  bf16_t* agg_i   = pool;                              // NI*DD
  bf16_t* agg_u   = agg_i + (size_t)NI * DD;           // NU*DD
  bf16_t* xb_item = agg_u + (size_t)NU * DD;           // NI*DD
  bf16_t* xb_user = xb_item + (size_t)NI * DD;         // NU*DD
  bf16_t* t_user  = pool;                              // NU*OO
  bf16_t* t_item  = t_user + (size_t)NU * OO;          // NI*OO
  bf16_t* h_item = (bf16_t*)(base + take((size_t)(NI + NU) * HH * 2));
  bf16_t* h_user = h_item + (size_t)NI * HH;
  bf16_t* z_item = (bf16_t*)(base + take((size_t)(NI + NU) * OO * 2));
  bf16_t* z_user = z_item + (size_t)NI * OO;
  bf16_t* Wt[8];
  for (int w = 0; w < 8; ++w) Wt[w] = (bf16_t*)(base + take((size_t)DD * HH * 2));
  size_t need = off;

  float* out = (float*)d_out;
  if (ws_size < need) {  // diagnostic: surface ws_size in MB via absmax
    probe_k<<<(L + 255) / 256, 256, 0, stream>>>(out, L, (float)(ws_size >> 20));
    return;
  }

  // ---- CSR build ----
  hipMemsetAsync(deg_i, 0, degB, stream);
  degree_k<<<(E + 255) / 256, 256, 0, stream>>>(edge_src, edge_dst, deg_u, deg_i, E);
  scan1_k<<<nb_i, 256, 0, stream>>>(deg_i, row_i, part_i, NI);
  scan1_k<<<nb_u, 256, 0, stream>>>(deg_u, row_u, part_u, NU);
  scan2_k<<<1, 1024, 0, stream>>>(part_i, nb_i);
  scan2_k<<<1, 1024, 0, stream>>>(part_u, nb_u);
  scan3_k<<<(NI + 255) / 256, 256, 0, stream>>>(row_i, part_i, NI, E);
  scan3_k<<<(NU + 255) / 256, 256, 0, stream>>>(row_u, part_u, NU, E);
  copy_cur_k<<<(NI + NU + 255) / 256, 256, 0, stream>>>(row_i, row_u, cur_i, cur_u, NI, NU);
  fill_csr_k<<<(E + 255) / 256, 256, 0, stream>>>(edge_src, edge_dst, cur_i, cur_u, csr_i, csr_u, E);

  // ---- dtype prep ----
  cvt_bf16_k<<<(NI * DD / 4 + 255) / 256, 256, 0, stream>>>(x_item, xb_item, NI * DD / 4);
  cvt_bf16_k<<<(NU * DD / 4 + 255) / 256, 256, 0, stream>>>(x_user, xb_user, NU * DD / 4);
  {
    dim3 g1(HH / 32, DD / 32);  // layer-1 weights [D,H] -> [H,D]
    for (int w = 0; w < 4; ++w) twconv_k<<<g1, 256, 0, stream>>>(W_raw[w], Wt[w], DD, HH);
    dim3 g2(OO / 32, HH / 32);  // layer-2 weights [H,O] -> [O,H]
    for (int w = 4; w < 8; ++w) twconv_k<<<g2, 256, 0, stream>>>(W_raw[w], Wt[w], HH, OO);
  }

  // ---- layer 1: gather-mean + dual GEMM ----
  gather_mean_k<DD, false><<<(NI * 64 + 255) / 256, 256, 0, stream>>>(row_i, csr_i, xb_user, agg_i, NI);
  gather_mean_k<DD, false><<<(NU * 64 + 255) / 256, 256, 0, stream>>>(row_u, csr_u, xb_item, agg_u, NU);
  {
    dim3 g(HH / 128, (NI + 127) / 128);
    mfma_gemm_k<true, true, true><<<g, 256, 0, stream>>>(NI, HH, DD, agg_i, xb_item, Wt[0], Wt[1], b1_ui, h_item);
    dim3 g2(HH / 128, (NU + 127) / 128);
    mfma_gemm_k<true, true, true><<<g2, 256, 0, stream>>>(NU, HH, DD, agg_u, xb_user, Wt[2], Wt[3], b1_iu, h_user);
  }

  // ---- layer 2 (re-associated): gather in O-space ----
  // t_user = h_user @ wl2_ui ; t_item = h_item @ wl2_iu
  {
    dim3 gtu(OO / 128, (NU + 127) / 128);
    mfma_gemm_k<false, false, false><<<gtu, 256, 0, stream>>>(NU, OO, HH, h_user, nullptr, Wt[4], nullptr, nullptr, t_user);
    dim3 gti(OO / 128, (NI + 127) / 128);
    mfma_gemm_k<false, false, false><<<gti, 256, 0, stream>>>(NI, OO, HH, h_item, nullptr, Wt[6], nullptr, nullptr, t_item);
  }
  // z_item = h_item @ wr2_ui + b2_ui ; z_user = h_user @ wr2_iu + b2_iu
  {
    dim3 gzi(OO / 128, (NI + 127) / 128);
    mfma_gemm_k<false, false, true><<<gzi, 256, 0, stream>>>(NI, OO, HH, h_item, nullptr, Wt[5], nullptr, b2_ui, z_item);
    dim3 gzu(OO / 128, (NU + 127) / 128);
    mfma_gemm_k<false, false, true><<<gzu, 256, 0, stream>>>(NU, OO, HH, h_user, nullptr, Wt[7], nullptr, b2_iu, z_user);
  }
  // z_item += mean(t_user[N(item)]) ; z_user += mean(t_item[N(user)])
  gather_mean_k<OO, true><<<(NI * 64 + 255) / 256, 256, 0, stream>>>(row_i, csr_i, t_user, z_item, NI);
  gather_mean_k<OO, true><<<(NU * 64 + 255) / 256, 256, 0, stream>>>(row_u, csr_u, t_item, z_user, NU);

  // ---- decode ----
  decode_k<<<(int)(((long long)L * 64 + 255) / 256), 256, 0, stream>>>(lbl_src, lbl_dst, z_user, z_item, out, L);
}

// Round 6
// 531.530 us; speedup vs baseline: 16.5016x; 1.1347x over previous
//
#include <hip/hip_runtime.h>

#define DD 128   // input feature dim D
#define HH 256   // hidden dim H
#define OO 128   // output dim O

// CSR bucket config (NI=50000 -> W=196<=320; NU=100000/512 -> W=196<=320)
#define NBI 256
#define NBU 512

typedef unsigned short bf16_t;
typedef short bf16x8 __attribute__((ext_vector_type(8)));   // 8 bf16 = 4 VGPRs
typedef float f32x4 __attribute__((ext_vector_type(4)));

__device__ __forceinline__ float bf2f(bf16_t u) {
  union { unsigned int i; float f; } v; v.i = ((unsigned int)u) << 16; return v.f;
}
__device__ __forceinline__ bf16_t f2bf(float f) {
  union { float f; unsigned int i; } v; v.f = f;
  unsigned int r = v.i + 0x7FFFu + ((v.i >> 16) & 1u);  // RNE
  return (bf16_t)(r >> 16);
}

// ---------------------------------------------------------------------------
__global__ void probe_k(float* __restrict__ out, int n, float v) {
  int i = blockIdx.x * blockDim.x + threadIdx.x;
  if (i < n) out[i] = v;
}

// ---------------- CSR build ----------------
// degrees + coarse bucket histograms in one pass (4096 edges/block)
__global__ __launch_bounds__(256) void degree_hist_k(
    const int* __restrict__ src, const int* __restrict__ dst,
    int* __restrict__ deg_u, int* __restrict__ deg_i,
    int* __restrict__ hist_u, int* __restrict__ hist_i,
    int E, int Wi, int Wu) {
  __shared__ int hi[NBI], hu[NBU];
  int tid = threadIdx.x;
  for (int t = tid; t < NBI; t += 256) hi[t] = 0;
  for (int t = tid; t < NBU; t += 256) hu[t] = 0;
  __syncthreads();
  int base = blockIdx.x * 4096;
#pragma unroll
  for (int j = 0; j < 16; ++j) {
    int e = base + tid + j * 256;
    if (e < E) {
      int s = src[e], d = dst[e];
      atomicAdd(deg_u + s, 1);
      atomicAdd(deg_i + d, 1);
      atomicAdd(&hi[d / Wi], 1);
      atomicAdd(&hu[s / Wu], 1);
    }
  }
  __syncthreads();
  for (int t = tid; t < NBI; t += 256) if (hi[t]) atomicAdd(hist_i + t, hi[t]);
  for (int t = tid; t < NBU; t += 256) if (hu[t]) atomicAdd(hist_u + t, hu[t]);
}

// node-degree exclusive scan (chunked)
__global__ void scan1_k(const int* __restrict__ deg, int* __restrict__ excl,
                        int* __restrict__ part, int n) {
  __shared__ int lds[256];
  int b = blockIdx.x, tid = threadIdx.x;
  int base = b * 1024;
  int v[4]; int s = 0;
#pragma unroll
  for (int j = 0; j < 4; ++j) { int i = base + tid * 4 + j; v[j] = (i < n) ? deg[i] : 0; s += v[j]; }
  lds[tid] = s; __syncthreads();
  for (int off = 1; off < 256; off <<= 1) {
    int t = (tid >= off) ? lds[tid - off] : 0;
    __syncthreads(); lds[tid] += t; __syncthreads();
  }
  int run = lds[tid] - s;
  if (tid == 255) part[b] = lds[255];
#pragma unroll
  for (int j = 0; j < 4; ++j) { int i = base + tid * 4 + j; if (i < n) excl[i] = run; run += v[j]; }
}

__global__ void scan2_k(int* __restrict__ part, int nb) {  // nb <= 1024
  __shared__ int lds[1024];
  int tid = threadIdx.x;
  int v = (tid < nb) ? part[tid] : 0;
  lds[tid] = v; __syncthreads();
  for (int off = 1; off < 1024; off <<= 1) {
    int t = (tid >= off) ? lds[tid - off] : 0;
    __syncthreads(); lds[tid] += t; __syncthreads();
  }
  if (tid < nb) part[tid] = lds[tid] - v;
}

__global__ void scan3_k(int* __restrict__ row, const int* __restrict__ part, int n, int Etot) {
  int i = blockIdx.x * blockDim.x + threadIdx.x;
  if (i < n) row[i] += part[i >> 10];
  if (i == 0) row[n] = Etot;
}

// bucket-histogram exclusive scan for both sides in one launch (block 0: item, 1: user)
__global__ __launch_bounds__(512) void scan_small_pair_k(
    const int* __restrict__ hist_i, int* __restrict__ off_i, int* __restrict__ cur_i,
    const int* __restrict__ hist_u, int* __restrict__ off_u, int* __restrict__ cur_u) {
  __shared__ int lds[512];
  const int* hist = blockIdx.x ? hist_u : hist_i;
  int* off = blockIdx.x ? off_u : off_i;
  int* cur = blockIdx.x ? cur_u : cur_i;
  int n = blockIdx.x ? NBU : NBI;
  int t = threadIdx.x;
  int v = (t < n) ? hist[t] : 0;
  lds[t] = v; __syncthreads();
  for (int o = 1; o < 512; o <<= 1) {
    int tv = (t >= o) ? lds[t - o] : 0;
    __syncthreads(); lds[t] += tv; __syncthreads();
  }
  if (t < n) { int e = lds[t] - v; off[t] = e; cur[t] = e; }
}

// block-aggregated bucket append: per block, reserve chunk per bucket with one
// global atomic, then write packed entries ((local<<24)|other) contiguously.
__global__ __launch_bounds__(256) void bucket_append_k(
    const int* __restrict__ src, const int* __restrict__ dst, int E, int Wi, int Wu,
    int* __restrict__ cur_bi, int* __restrict__ cur_bu,
    unsigned int* __restrict__ ebuf_i, unsigned int* __restrict__ ebuf_u) {
  __shared__ int bi[NBI], bu[NBU];
  __shared__ uint2 es[4096];
  int tid = threadIdx.x;
  int base = blockIdx.x * 4096;
  int n = E - base; if (n > 4096) n = 4096;
  for (int t = tid; t < NBI; t += 256) bi[t] = 0;
  for (int t = tid; t < NBU; t += 256) bu[t] = 0;
  __syncthreads();
#pragma unroll
  for (int j = 0; j < 16; ++j) {
    int idx = tid + j * 256;
    if (idx < n) {
      int s = src[base + idx], d = dst[base + idx];
      es[idx] = make_uint2((unsigned)s, (unsigned)d);
      atomicAdd(&bi[d / Wi], 1);
      atomicAdd(&bu[s / Wu], 1);
    }
  }
  __syncthreads();
  for (int t = tid; t < NBI; t += 256) { int c = bi[t]; bi[t] = c ? atomicAdd(cur_bi + t, c) : 0; }
  for (int t = tid; t < NBU; t += 256) { int c = bu[t]; bu[t] = c ? atomicAdd(cur_bu + t, c) : 0; }
  __syncthreads();
#pragma unroll
  for (int j = 0; j < 16; ++j) {
    int idx = tid + j * 256;
    if (idx < n) {
      int s = (int)es[idx].x, d = (int)es[idx].y;
      int bI = d / Wi, bU = s / Wu;
      int pI = atomicAdd(&bi[bI], 1);
      int pU = atomicAdd(&bu[bU], 1);
      ebuf_i[pI] = ((unsigned)(d - bI * Wi) << 24) | (unsigned)s;
      ebuf_u[pU] = ((unsigned)(s - bU * Wu) << 24) | (unsigned)d;
    }
  }
}

// per-bucket CSR fill: one block owns one contiguous csr slice (single XCD)
__global__ __launch_bounds__(256) void bucket_fill_k(
    const unsigned int* __restrict__ ebuf, const int* __restrict__ off,
    const int* __restrict__ endc, const int* __restrict__ row,
    int* __restrict__ csr, int n, int W) {
  int b = blockIdx.x;
  int d0 = b * W; if (d0 >= n) return;
  int cnt = n - d0; if (cnt > W) cnt = W;
  __shared__ int cur[320];
  for (int t = threadIdx.x; t < cnt; t += 256) cur[t] = row[d0 + t];
  __syncthreads();
  int beg = off[b], e_end = endc[b];
  for (int e = beg + threadIdx.x; e < e_end; e += 256) {
    unsigned v = ebuf[e];
    int dloc = (int)(v >> 24);
    int s = (int)(v & 0xFFFFFFu);
    int slot = atomicAdd(&cur[dloc], 1);
    csr[slot] = s;
  }
}

// ---------------- dtype prep ----------------
__global__ void cvt_bf16_k(const float* __restrict__ in, bf16_t* __restrict__ out, int n4) {
  int i = blockIdx.x * blockDim.x + threadIdx.x;
  if (i < n4) {
    float4 v = ((const float4*)in)[i];
    ushort4 o; o.x = f2bf(v.x); o.y = f2bf(v.y); o.z = f2bf(v.z); o.w = f2bf(v.w);
    ((ushort4*)out)[i] = o;
  }
}

// batched transpose-convert: f32 [K,N] row-major -> bf16 [N,K] row-major
struct WBatch { const float* in[4]; bf16_t* out[4]; };
__global__ void twconv_batch_k(WBatch wb, int K, int N) {
  const float* __restrict__ in = wb.in[blockIdx.z];
  bf16_t* __restrict__ out = wb.out[blockIdx.z];
  __shared__ float t[32][33];
  int bx = blockIdx.x * 32, by = blockIdx.y * 32;
  int tx = threadIdx.x & 31, ty = threadIdx.x >> 5;  // 32x8
#pragma unroll
  for (int j = 0; j < 32; j += 8)
    t[ty + j][tx] = in[(size_t)(by + ty + j) * N + bx + tx];
  __syncthreads();
#pragma unroll
  for (int j = 0; j < 32; j += 8)
    out[(size_t)(bx + ty + j) * K + by + tx] = f2bf(t[tx][ty + j]);
}

// ---------------- gather-mean (bf16 source) ----------------
template<int V>
__device__ __forceinline__ void loadrow(float* t, const bf16_t* X, int idx, int lane) {
  const bf16_t* p = X + (size_t)idx * (V * 64) + lane * V;
  if (V == 4) {
    ushort4 u = *(const ushort4*)p;
    t[0] = bf2f(u.x); t[1] = bf2f(u.y); t[2] = bf2f(u.z); t[3] = bf2f(u.w);
  } else {
    ushort2 u = *(const ushort2*)p; t[0] = bf2f(u.x); t[1] = bf2f(u.y);
  }
}

// ADD=false: agg[node] = mean(X[nbrs]).  ADD=true: agg[node] += mean(X[nbrs]).
template<int D, bool ADD>
__global__ void gather_mean_k(const int* __restrict__ row, const int* __restrict__ csr,
                              const bf16_t* __restrict__ X, bf16_t* __restrict__ agg, int n) {
  constexpr int V = D / 64;
  int node = (int)(((long long)blockIdx.x * blockDim.x + threadIdx.x) >> 6);
  int lane = threadIdx.x & 63;
  if (node >= n) return;
  int beg = row[node], end = row[node + 1];
  float acc[V] = {};
  for (int j0 = beg; j0 < end; j0 += 64) {
    int my = (j0 + lane < end) ? csr[j0 + lane] : 0;
    int cnt = min(64, end - j0);
    int k = 0;
    for (; k + 4 <= cnt; k += 4) {
      int i0 = __shfl(my, k), i1 = __shfl(my, k + 1);
      int i2 = __shfl(my, k + 2), i3 = __shfl(my, k + 3);
      float t0[V], t1[V], t2[V], t3[V];
      loadrow<V>(t0, X, i0, lane);
      loadrow<V>(t1, X, i1, lane);
      loadrow<V>(t2, X, i2, lane);
      loadrow<V>(t3, X, i3, lane);
#pragma unroll
      for (int v = 0; v < V; ++v) acc[v] += (t0[v] + t1[v]) + (t2[v] + t3[v]);
    }
    for (; k < cnt; ++k) {
      int i0 = __shfl(my, k);
      float t0[V];
      loadrow<V>(t0, X, i0, lane);
#pragma unroll
      for (int v = 0; v < V; ++v) acc[v] += t0[v];
    }
  }
  float inv = (end > beg) ? 1.0f / (float)(end - beg) : 0.0f;
  bf16_t* po = agg + (size_t)node * D + lane * V;
  if (V == 4) {
    float b0 = 0, b1 = 0, b2 = 0, b3 = 0;
    if (ADD) { ushort4 z = *(const ushort4*)po; b0 = bf2f(z.x); b1 = bf2f(z.y); b2 = bf2f(z.z); b3 = bf2f(z.w); }
    ushort4 o; o.x = f2bf(acc[0] * inv + b0); o.y = f2bf(acc[1] * inv + b1);
    o.z = f2bf(acc[2] * inv + b2); o.w = f2bf(acc[3] * inv + b3);
    *(ushort4*)po = o;
  } else {
    float b0 = 0, b1 = 0;
    if (ADD) { ushort2 z = *(const ushort2*)po; b0 = bf2f(z.x); b1 = bf2f(z.y); }
    ushort2 o; o.x = f2bf(acc[0] * inv + b0); o.y = f2bf(acc[1] * inv + b1);
    *(ushort2*)po = o;
  }
}

// ---------------- MFMA GEMM ----------------
// C = act( A1 @ W1 [+ A2 @ W2] [+ bias] ), A* bf16 [M,K] row-major,
// W*t bf16 [N,K] row-major. 128x128 tile, 4 waves, BK=32, global_load_lds.
// SPLIT: N=256 logical; blocks with col0<128 write C (stride 128, +bias),
//        col0>=128 write C2 (stride 128, no bias).
template<bool RELU, bool DUAL, bool BIAS, bool SPLIT>
__global__ __launch_bounds__(256) void mfma_gemm_k(
    int M, int N, int K,
    const bf16_t* __restrict__ A1, const bf16_t* __restrict__ A2,
    const bf16_t* __restrict__ W1t, const bf16_t* __restrict__ W2t,
    const float* __restrict__ bias, bf16_t* __restrict__ C, bf16_t* __restrict__ C2) {
  __shared__ __align__(16) bf16_t Als[128 * 32];  // [row][k] 64B rows
  __shared__ __align__(16) bf16_t Bls[128 * 32];  // [col][k]
  const int tid = threadIdx.x;
  const int wave = tid >> 6, lane = tid & 63;
  const int wr = wave >> 1, wc = wave & 1;
  const size_t row0 = (size_t)blockIdx.y * 128;
  const int col0 = blockIdx.x * 128;

  f32x4 acc[4][4] = {};

  const int fbase = wave * 2048 + lane * 16;  // byte offset of this lane's 16B slot

  for (int s = 0; s < (DUAL ? 2 : 1); ++s) {
    const bf16_t* __restrict__ Ap = s ? A2 : A1;
    const bf16_t* __restrict__ Wp = s ? W2t : W1t;
    for (int k0 = 0; k0 < K; k0 += 32) {
#pragma unroll
      for (int seg = 0; seg < 2; ++seg) {
        const int f = fbase + seg * 1024;
        const int r = f >> 6;              // tile row/col 0..127
        const int ke = (f & 63) >> 1;      // element offset within 32-elem k-slice
        size_t ar = row0 + r; if (ar >= (size_t)M) ar = M - 1;
        __builtin_amdgcn_global_load_lds(
            (const __attribute__((address_space(1))) void*)(Ap + ar * K + k0 + ke),
            (__attribute__((address_space(3))) void*)(Als + (f >> 1)), 16, 0, 0);
        __builtin_amdgcn_global_load_lds(
            (const __attribute__((address_space(1))) void*)(Wp + (size_t)(col0 + r) * K + k0 + ke),
            (__attribute__((address_space(3))) void*)(Bls + (f >> 1)), 16, 0, 0);
      }
      __syncthreads();
      const int aoff = (wr * 64 + (lane & 15)) * 32 + (lane >> 4) * 8;
      const int boff = (wc * 64 + (lane & 15)) * 32 + (lane >> 4) * 8;
      bf16x8 af[4], bfr[4];
#pragma unroll
      for (int i = 0; i < 4; ++i) {
        af[i] = *(const bf16x8*)(Als + aoff + i * 16 * 32);
        bfr[i] = *(const bf16x8*)(Bls + boff + i * 16 * 32);
      }
#pragma unroll
      for (int mi = 0; mi < 4; ++mi)
#pragma unroll
        for (int ni = 0; ni < 4; ++ni)
          acc[mi][ni] = __builtin_amdgcn_mfma_f32_16x16x32_bf16(af[mi], bfr[ni], acc[mi][ni], 0, 0, 0);
      __syncthreads();
    }
  }

  const int crow = wr * 64 + (lane >> 4) * 4;
  int ccol = col0 + wc * 64 + (lane & 15);
  bf16_t* Co = C;
  int stride = N;
  bool useBias = BIAS;
  if (SPLIT) {
    const int half = N >> 1;
    stride = half;
    if (col0 >= half) { Co = C2; ccol -= half; useBias = false; }
  }
#pragma unroll
  for (int mi = 0; mi < 4; ++mi) {
#pragma unroll
    for (int j = 0; j < 4; ++j) {
      size_t r = row0 + crow + mi * 16 + j;
      if (r < (size_t)M) {
#pragma unroll
        for (int ni = 0; ni < 4; ++ni) {
          float v = acc[mi][ni][j];
          if (BIAS) { if (useBias) v += bias[ccol + ni * 16]; }
          if (RELU) v = fmaxf(v, 0.f);
          Co[r * stride + ccol + ni * 16] = f2bf(v);
        }
      }
    }
  }
}

// ---------------- decode ----------------
__global__ void decode_k(const int* __restrict__ ls, const int* __restrict__ ld,
                         const bf16_t* __restrict__ zu, const bf16_t* __restrict__ zi,
                         float* __restrict__ out, int L) {
  int w = (int)(((long long)blockIdx.x * blockDim.x + threadIdx.x) >> 6);
  int lane = threadIdx.x & 63;
  if (w >= L) return;
  int su = ls[w], si = ld[w];
  ushort2 u = *(const ushort2*)(zu + (size_t)su * OO + lane * 2);
  ushort2 v = *(const ushort2*)(zi + (size_t)si * OO + lane * 2);
  float sum = bf2f(u.x) * bf2f(v.x) + bf2f(u.y) * bf2f(v.y);
#pragma unroll
  for (int off = 32; off; off >>= 1) sum += __shfl_xor(sum, off);
  if (lane == 0) out[w] = sum;
}

// ---------------------------------------------------------------------------
extern "C" void kernel_launch(void* const* d_in, const int* in_sizes, int n_in,
                              void* d_out, int out_size, void* d_ws, size_t ws_size,
                              hipStream_t stream) {
  const float* x_user = (const float*)d_in[0];
  const float* x_item = (const float*)d_in[1];
  const int* edge_src = (const int*)d_in[2];
  const int* edge_dst = (const int*)d_in[3];
  const int* lbl_src  = (const int*)d_in[4];
  const int* lbl_dst  = (const int*)d_in[5];
  const float* wl1_ui = (const float*)d_in[6];
  const float* wr1_ui = (const float*)d_in[7];
  const float* b1_ui  = (const float*)d_in[8];
  const float* wl1_iu = (const float*)d_in[9];
  const float* wr1_iu = (const float*)d_in[10];
  const float* b1_iu  = (const float*)d_in[11];
  const float* wl2_ui = (const float*)d_in[12];
  const float* wr2_ui = (const float*)d_in[13];
  const float* b2_ui  = (const float*)d_in[14];
  const float* wl2_iu = (const float*)d_in[15];
  const float* wr2_iu = (const float*)d_in[16];
  const float* b2_iu  = (const float*)d_in[17];

  const int NU = in_sizes[0] / DD;
  const int NI = in_sizes[1] / DD;
  const int E  = in_sizes[2];
  const int L  = in_sizes[4];
  const int nb_i = (NI + 1023) / 1024, nb_u = (NU + 1023) / 1024;
  const int Wi = (NI + NBI - 1) / NBI;   // bucket width (<=320 for LDS cur)
  const int Wu = (NU + NBU - 1) / NBU;
  const int nEB = (E + 4095) / 4096;

  // ---- workspace layout ----
  size_t off = 0;
  auto take = [&](size_t bytes) { size_t o = off; off = (off + bytes + 255) & ~(size_t)255; return o; };
  char* base = (char*)d_ws;
  // zeroed-together block: deg_i, deg_u, hist_i, hist_u
  int* deg_i = (int*)(base + take(((size_t)NI + NU + NBI + NBU) * 4));
  int* deg_u  = deg_i + NI;
  int* hist_i = deg_u + NU;
  int* hist_u = hist_i + NBI;
  size_t zeroB = ((size_t)NI + NU + NBI + NBU) * 4;
  int* row_i = (int*)(base + take((size_t)(NI + 1) * 4));
  int* row_u = (int*)(base + take((size_t)(NU + 1) * 4));
  int* part_i = (int*)(base + take((size_t)nb_i * 4));
  int* part_u = (int*)(base + take((size_t)nb_u * 4));
  int* off_i = (int*)(base + take((size_t)NBI * 4));
  int* off_u = (int*)(base + take((size_t)NBU * 4));
  int* cur_bi = (int*)(base + take((size_t)NBI * 4));
  int* cur_bu = (int*)(base + take((size_t)NBU * 4));
  int* csr_i = (int*)(base + take((size_t)E * 4));
  int* csr_u = (int*)(base + take((size_t)E * 4));
  unsigned int* ebuf_i = (unsigned int*)(base + take((size_t)E * 4));
  unsigned int* ebuf_u = (unsigned int*)(base + take((size_t)E * 4));
  // pool: (NI+NU)*HH bf16.
  //  layer 1: agg_i|agg_u|xb_item|xb_user (exactly fills)
  //  layer 2: t_user|t_item (overlays; layer-1 tenants dead)
  bf16_t* pool = (bf16_t*)(base + take((size_t)(NI + NU) * HH * 2));
  bf16_t* agg_i   = pool;                              // NI*DD
  bf16_t* agg_u   = agg_i + (size_t)NI * DD;           // NU*DD
  bf16_t* xb_item = agg_u + (size_t)NU * DD;           // NI*DD
  bf16_t* xb_user = xb_item + (size_t)NI * DD;         // NU*DD
  bf16_t* t_user  = pool;                              // NU*OO
  bf16_t* t_item  = t_user + (size_t)NU * OO;          // NI*OO
  bf16_t* h_item = (bf16_t*)(base + take((size_t)(NI + NU) * HH * 2));
  bf16_t* h_user = h_item + (size_t)NI * HH;
  bf16_t* z_item = (bf16_t*)(base + take((size_t)(NI + NU) * OO * 2));
  bf16_t* z_user = z_item + (size_t)NI * OO;
  // weights: 4x layer-1 [HH,DD] + 2x layer-2 concat [2*OO, HH]
  bf16_t* Wt1[4];
  for (int w = 0; w < 4; ++w) Wt1[w] = (bf16_t*)(base + take((size_t)HH * DD * 2));
  bf16_t* Wcat_item = (bf16_t*)(base + take((size_t)2 * OO * HH * 2));
  bf16_t* Wcat_user = (bf16_t*)(base + take((size_t)2 * OO * HH * 2));
  size_t need = off;

  float* out = (float*)d_out;
  if (ws_size < need || Wi > 320 || Wu > 320) {
    probe_k<<<(L + 255) / 256, 256, 0, stream>>>(out, L, (float)(ws_size >> 20));
    return;
  }

  // ---- CSR build ----
  hipMemsetAsync(deg_i, 0, zeroB, stream);
  degree_hist_k<<<nEB, 256, 0, stream>>>(edge_src, edge_dst, deg_u, deg_i, hist_u, hist_i, E, Wi, Wu);
  scan1_k<<<nb_i, 256, 0, stream>>>(deg_i, row_i, part_i, NI);
  scan1_k<<<nb_u, 256, 0, stream>>>(deg_u, row_u, part_u, NU);
  scan2_k<<<1, 1024, 0, stream>>>(part_i, nb_i);
  scan2_k<<<1, 1024, 0, stream>>>(part_u, nb_u);
  scan3_k<<<(NI + 255) / 256, 256, 0, stream>>>(row_i, part_i, NI, E);
  scan3_k<<<(NU + 255) / 256, 256, 0, stream>>>(row_u, part_u, NU, E);
  scan_small_pair_k<<<2, 512, 0, stream>>>(hist_i, off_i, cur_bi, hist_u, off_u, cur_bu);
  bucket_append_k<<<nEB, 256, 0, stream>>>(edge_src, edge_dst, E, Wi, Wu, cur_bi, cur_bu, ebuf_i, ebuf_u);
  bucket_fill_k<<<NBI, 256, 0, stream>>>(ebuf_i, off_i, cur_bi, row_i, csr_i, NI, Wi);
  bucket_fill_k<<<NBU, 256, 0, stream>>>(ebuf_u, off_u, cur_bu, row_u, csr_u, NU, Wu);

  // ---- dtype prep ----
  cvt_bf16_k<<<(NI * DD / 4 + 255) / 256, 256, 0, stream>>>(x_item, xb_item, NI * DD / 4);
  cvt_bf16_k<<<(NU * DD / 4 + 255) / 256, 256, 0, stream>>>(x_user, xb_user, NU * DD / 4);
  {
    WBatch w1;
    w1.in[0] = wl1_ui; w1.out[0] = Wt1[0];
    w1.in[1] = wr1_ui; w1.out[1] = Wt1[1];
    w1.in[2] = wl1_iu; w1.out[2] = Wt1[2];
    w1.in[3] = wr1_iu; w1.out[3] = Wt1[3];
    dim3 g1(HH / 32, DD / 32, 4);  // [D,H] -> [H,D]
    twconv_batch_k<<<g1, 256, 0, stream>>>(w1, DD, HH);
    WBatch w2;
    w2.in[0] = wr2_ui; w2.out[0] = Wcat_item;             // z_item part
    w2.in[1] = wl2_iu; w2.out[1] = Wcat_item + (size_t)OO * HH;  // t_item part
    w2.in[2] = wr2_iu; w2.out[2] = Wcat_user;             // z_user part
    w2.in[3] = wl2_ui; w2.out[3] = Wcat_user + (size_t)OO * HH;  // t_user part
    dim3 g2(OO / 32, HH / 32, 4);  // [H,O] -> [O,H]
    twconv_batch_k<<<g2, 256, 0, stream>>>(w2, HH, OO);
  }

  // ---- layer 1: gather-mean + dual GEMM ----
  gather_mean_k<DD, false><<<(NI * 64 + 255) / 256, 256, 0, stream>>>(row_i, csr_i, xb_user, agg_i, NI);
  gather_mean_k<DD, false><<<(NU * 64 + 255) / 256, 256, 0, stream>>>(row_u, csr_u, xb_item, agg_u, NU);
  {
    dim3 g(HH / 128, (NI + 127) / 128);
    mfma_gemm_k<true, true, true, false><<<g, 256, 0, stream>>>(
        NI, HH, DD, agg_i, xb_item, Wt1[0], Wt1[1], b1_ui, h_item, nullptr);
    dim3 g2(HH / 128, (NU + 127) / 128);
    mfma_gemm_k<true, true, true, false><<<g2, 256, 0, stream>>>(
        NU, HH, DD, agg_u, xb_user, Wt1[2], Wt1[3], b1_iu, h_user, nullptr);
  }

  // ---- layer 2 (re-associated, merged split GEMMs) ----
  // item side: z_item = h_item @ wr2_ui + b2_ui ; t_item = h_item @ wl2_iu
  {
    dim3 g(2, (NI + 127) / 128);
    mfma_gemm_k<false, false, true, true><<<g, 256, 0, stream>>>(
        NI, 2 * OO, HH, h_item, nullptr, Wcat_item, nullptr, b2_ui, z_item, t_item);
    dim3 g2(2, (NU + 127) / 128);
    mfma_gemm_k<false, false, true, true><<<g2, 256, 0, stream>>>(
        NU, 2 * OO, HH, h_user, nullptr, Wcat_user, nullptr, b2_iu, z_user, t_user);
  }
  // z_item += mean(t_user[N(item)]) ; z_user += mean(t_item[N(user)])
  gather_mean_k<OO, true><<<(NI * 64 + 255) / 256, 256, 0, stream>>>(row_i, csr_i, t_user, z_item, NI);
  gather_mean_k<OO, true><<<(NU * 64 + 255) / 256, 256, 0, stream>>>(row_u, csr_u, t_item, z_user, NU);

  // ---- decode ----
  decode_k<<<(int)(((long long)L * 64 + 255) / 256), 256, 0, stream>>>(lbl_src, lbl_dst, z_user, z_item, out, L);
}

// Round 7
// 488.268 us; speedup vs baseline: 17.9636x; 1.0886x over previous
//
#include <hip/hip_runtime.h>

#define DD 128   // input feature dim D
#define HH 256   // hidden dim H
#define OO 128   // output dim O

// CSR bucket config
#define NBI 256
#define NBU 512

typedef unsigned short bf16_t;
typedef short bf16x8 __attribute__((ext_vector_type(8)));   // 8 bf16 = 4 VGPRs
typedef float f32x4 __attribute__((ext_vector_type(4)));

__device__ __forceinline__ float bf2f(bf16_t u) {
  union { unsigned int i; float f; } v; v.i = ((unsigned int)u) << 16; return v.f;
}
__device__ __forceinline__ bf16_t f2bf(float f) {
  union { float f; unsigned int i; } v; v.f = f;
  unsigned int r = v.i + 0x7FFFu + ((v.i >> 16) & 1u);  // RNE
  return (bf16_t)(r >> 16);
}

// unpack a u32 holding 2 bf16 into 2 floats: lo = u<<16, hi = u & 0xffff0000
__device__ __forceinline__ void acc8(float* acc, uint4 u) {
  const unsigned* p = (const unsigned*)&u;
#pragma unroll
  for (int i = 0; i < 4; ++i) {
    union { unsigned v; float f; } lo, hi;
    lo.v = p[i] << 16;
    hi.v = p[i] & 0xffff0000u;
    acc[2 * i] += lo.f;
    acc[2 * i + 1] += hi.f;
  }
}
__device__ __forceinline__ void unpack8(float* o, uint4 u) {
  const unsigned* p = (const unsigned*)&u;
#pragma unroll
  for (int i = 0; i < 4; ++i) {
    union { unsigned v; float f; } lo, hi;
    lo.v = p[i] << 16;
    hi.v = p[i] & 0xffff0000u;
    o[2 * i] = lo.f;
    o[2 * i + 1] = hi.f;
  }
}
__device__ __forceinline__ uint4 pack8(const float* v) {
  uint4 o; unsigned* p = (unsigned*)&o;
#pragma unroll
  for (int i = 0; i < 4; ++i)
    p[i] = (unsigned)f2bf(v[2 * i]) | ((unsigned)f2bf(v[2 * i + 1]) << 16);
  return o;
}

// ---------------------------------------------------------------------------
__global__ void probe_k(float* __restrict__ out, int n, float v) {
  int i = blockIdx.x * blockDim.x + threadIdx.x;
  if (i < n) out[i] = v;
}

// ---------------- CSR build ----------------
__global__ __launch_bounds__(256) void degree_hist_k(
    const int* __restrict__ src, const int* __restrict__ dst,
    int* __restrict__ deg_u, int* __restrict__ deg_i,
    int* __restrict__ hist_u, int* __restrict__ hist_i,
    int E, int Wi, int Wu) {
  __shared__ int hi[NBI], hu[NBU];
  int tid = threadIdx.x;
  for (int t = tid; t < NBI; t += 256) hi[t] = 0;
  for (int t = tid; t < NBU; t += 256) hu[t] = 0;
  __syncthreads();
  int base = blockIdx.x * 4096;
#pragma unroll
  for (int j = 0; j < 16; ++j) {
    int e = base + tid + j * 256;
    if (e < E) {
      int s = src[e], d = dst[e];
      atomicAdd(deg_u + s, 1);
      atomicAdd(deg_i + d, 1);
      atomicAdd(&hi[d / Wi], 1);
      atomicAdd(&hu[s / Wu], 1);
    }
  }
  __syncthreads();
  for (int t = tid; t < NBI; t += 256) if (hi[t]) atomicAdd(hist_i + t, hi[t]);
  for (int t = tid; t < NBU; t += 256) if (hu[t]) atomicAdd(hist_u + t, hu[t]);
}

__global__ void scan1_k(const int* __restrict__ deg, int* __restrict__ excl,
                        int* __restrict__ part, int n) {
  __shared__ int lds[256];
  int b = blockIdx.x, tid = threadIdx.x;
  int base = b * 1024;
  int v[4]; int s = 0;
#pragma unroll
  for (int j = 0; j < 4; ++j) { int i = base + tid * 4 + j; v[j] = (i < n) ? deg[i] : 0; s += v[j]; }
  lds[tid] = s; __syncthreads();
  for (int off = 1; off < 256; off <<= 1) {
    int t = (tid >= off) ? lds[tid - off] : 0;
    __syncthreads(); lds[tid] += t; __syncthreads();
  }
  int run = lds[tid] - s;
  if (tid == 255) part[b] = lds[255];
#pragma unroll
  for (int j = 0; j < 4; ++j) { int i = base + tid * 4 + j; if (i < n) excl[i] = run; run += v[j]; }
}

__global__ void scan2_k(int* __restrict__ part, int nb) {  // nb <= 1024
  __shared__ int lds[1024];
  int tid = threadIdx.x;
  int v = (tid < nb) ? part[tid] : 0;
  lds[tid] = v; __syncthreads();
  for (int off = 1; off < 1024; off <<= 1) {
    int t = (tid >= off) ? lds[tid - off] : 0;
    __syncthreads(); lds[tid] += t; __syncthreads();
  }
  if (tid < nb) part[tid] = lds[tid] - v;
}

__global__ void scan3_k(int* __restrict__ row, const int* __restrict__ part, int n, int Etot) {
  int i = blockIdx.x * blockDim.x + threadIdx.x;
  if (i < n) row[i] += part[i >> 10];
  if (i == 0) row[n] = Etot;
}

__global__ __launch_bounds__(512) void scan_small_pair_k(
    const int* __restrict__ hist_i, int* __restrict__ off_i, int* __restrict__ cur_i,
    const int* __restrict__ hist_u, int* __restrict__ off_u, int* __restrict__ cur_u) {
  __shared__ int lds[512];
  const int* hist = blockIdx.x ? hist_u : hist_i;
  int* off = blockIdx.x ? off_u : off_i;
  int* cur = blockIdx.x ? cur_u : cur_i;
  int n = blockIdx.x ? NBU : NBI;
  int t = threadIdx.x;
  int v = (t < n) ? hist[t] : 0;
  lds[t] = v; __syncthreads();
  for (int o = 1; o < 512; o <<= 1) {
    int tv = (t >= o) ? lds[t - o] : 0;
    __syncthreads(); lds[t] += tv; __syncthreads();
  }
  if (t < n) { int e = lds[t] - v; off[t] = e; cur[t] = e; }
}

__global__ __launch_bounds__(256) void bucket_append_k(
    const int* __restrict__ src, const int* __restrict__ dst, int E, int Wi, int Wu,
    int* __restrict__ cur_bi, int* __restrict__ cur_bu,
    unsigned int* __restrict__ ebuf_i, unsigned int* __restrict__ ebuf_u) {
  __shared__ int bi[NBI], bu[NBU];
  __shared__ uint2 es[4096];
  int tid = threadIdx.x;
  int base = blockIdx.x * 4096;
  int n = E - base; if (n > 4096) n = 4096;
  for (int t = tid; t < NBI; t += 256) bi[t] = 0;
  for (int t = tid; t < NBU; t += 256) bu[t] = 0;
  __syncthreads();
#pragma unroll
  for (int j = 0; j < 16; ++j) {
    int idx = tid + j * 256;
    if (idx < n) {
      int s = src[base + idx], d = dst[base + idx];
      es[idx] = make_uint2((unsigned)s, (unsigned)d);
      atomicAdd(&bi[d / Wi], 1);
      atomicAdd(&bu[s / Wu], 1);
    }
  }
  __syncthreads();
  for (int t = tid; t < NBI; t += 256) { int c = bi[t]; bi[t] = c ? atomicAdd(cur_bi + t, c) : 0; }
  for (int t = tid; t < NBU; t += 256) { int c = bu[t]; bu[t] = c ? atomicAdd(cur_bu + t, c) : 0; }
  __syncthreads();
#pragma unroll
  for (int j = 0; j < 16; ++j) {
    int idx = tid + j * 256;
    if (idx < n) {
      int s = (int)es[idx].x, d = (int)es[idx].y;
      int bI = d / Wi, bU = s / Wu;
      int pI = atomicAdd(&bi[bI], 1);
      int pU = atomicAdd(&bu[bU], 1);
      ebuf_i[pI] = ((unsigned)(d - bI * Wi) << 24) | (unsigned)s;
      ebuf_u[pU] = ((unsigned)(s - bU * Wu) << 24) | (unsigned)d;
    }
  }
}

__global__ __launch_bounds__(256) void bucket_fill_k(
    const unsigned int* __restrict__ ebuf, const int* __restrict__ off,
    const int* __restrict__ endc, const int* __restrict__ row,
    int* __restrict__ csr, int n, int W) {
  int b = blockIdx.x;
  int d0 = b * W; if (d0 >= n) return;
  int cnt = n - d0; if (cnt > W) cnt = W;
  __shared__ int cur[320];
  for (int t = threadIdx.x; t < cnt; t += 256) cur[t] = row[d0 + t];
  __syncthreads();
  int beg = off[b], e_end = endc[b];
  for (int e = beg + threadIdx.x; e < e_end; e += 256) {
    unsigned v = ebuf[e];
    int dloc = (int)(v >> 24);
    int s = (int)(v & 0xFFFFFFu);
    int slot = atomicAdd(&cur[dloc], 1);
    csr[slot] = s;
  }
}

// ---------------- dtype prep ----------------
__global__ void cvt_bf16_k(const float* __restrict__ in, bf16_t* __restrict__ out, int n4) {
  int i = blockIdx.x * blockDim.x + threadIdx.x;
  if (i < n4) {
    float4 v = ((const float4*)in)[i];
    ushort4 o; o.x = f2bf(v.x); o.y = f2bf(v.y); o.z = f2bf(v.z); o.w = f2bf(v.w);
    ((ushort4*)out)[i] = o;
  }
}

struct WBatch { const float* in[4]; bf16_t* out[4]; };
__global__ void twconv_batch_k(WBatch wb, int K, int N) {
  const float* __restrict__ in = wb.in[blockIdx.z];
  bf16_t* __restrict__ out = wb.out[blockIdx.z];
  __shared__ float t[32][33];
  int bx = blockIdx.x * 32, by = blockIdx.y * 32;
  int tx = threadIdx.x & 31, ty = threadIdx.x >> 5;  // 32x8
#pragma unroll
  for (int j = 0; j < 32; j += 8)
    t[ty + j][tx] = in[(size_t)(by + ty + j) * N + bx + tx];
  __syncthreads();
#pragma unroll
  for (int j = 0; j < 32; j += 8)
    out[(size_t)(bx + ty + j) * K + by + tx] = f2bf(t[tx][ty + j]);
}

// ---------------- gather-mean, D=128, 16 lanes/row, 4 rows in flight ----------
// ADD=false: agg[node] = mean(X[nbrs]).  ADD=true: agg[node] += mean(X[nbrs]).
template<bool ADD>
__global__ void gather_mean16_k(const int* __restrict__ row, const int* __restrict__ csr,
                                const bf16_t* __restrict__ X, bf16_t* __restrict__ agg, int n) {
  int node = (int)(((long long)blockIdx.x * blockDim.x + threadIdx.x) >> 6);
  int lane = threadIdx.x & 63;
  if (node >= n) return;
  const int g = lane >> 4;      // group 0..3 (one neighbor row each)
  const int l = lane & 15;      // 16 lanes x 16B = 256B row
  int beg = row[node], end = row[node + 1];
  float acc[8] = {};
  for (int j0 = beg; j0 < end; j0 += 64) {
    int cnt = min(64, end - j0);
    int my = (lane < cnt) ? csr[j0 + lane] : 0;
    for (int k = 0; k < cnt; k += 4) {
      int idx = __shfl(my, k + g);
      if (k + g < cnt) {
        uint4 u = *(const uint4*)(X + (size_t)idx * 128 + l * 8);
        acc8(acc, u);
      }
    }
  }
  // cross-group reduce (mask 16, 32)
#pragma unroll
  for (int m = 16; m < 64; m <<= 1)
#pragma unroll
    for (int i = 0; i < 8; ++i) acc[i] += __shfl_xor(acc[i], m);
  if (g == 0) {
    float inv = (end > beg) ? 1.0f / (float)(end - beg) : 0.0f;
    float v[8];
    if (ADD) {
      uint4 z = *(const uint4*)(agg + (size_t)node * 128 + l * 8);
      float zb[8]; unpack8(zb, z);
#pragma unroll
      for (int i = 0; i < 8; ++i) v[i] = acc[i] * inv + zb[i];
    } else {
#pragma unroll
      for (int i = 0; i < 8; ++i) v[i] = acc[i] * inv;
    }
    *(uint4*)(agg + (size_t)node * 128 + l * 8) = pack8(v);
  }
}

// ---------------- MFMA GEMM ----------------
template<bool RELU, bool DUAL, bool BIAS, bool SPLIT>
__global__ __launch_bounds__(256) void mfma_gemm_k(
    int M, int N, int K,
    const bf16_t* __restrict__ A1, const bf16_t* __restrict__ A2,
    const bf16_t* __restrict__ W1t, const bf16_t* __restrict__ W2t,
    const float* __restrict__ bias, bf16_t* __restrict__ C, bf16_t* __restrict__ C2) {
  __shared__ __align__(16) bf16_t Als[128 * 32];  // [row][k] 64B rows
  __shared__ __align__(16) bf16_t Bls[128 * 32];  // [col][k]
  const int tid = threadIdx.x;
  const int wave = tid >> 6, lane = tid & 63;
  const int wr = wave >> 1, wc = wave & 1;
  const size_t row0 = (size_t)blockIdx.y * 128;
  const int col0 = blockIdx.x * 128;

  f32x4 acc[4][4] = {};

  const int fbase = wave * 2048 + lane * 16;  // byte offset of this lane's 16B slot

  for (int s = 0; s < (DUAL ? 2 : 1); ++s) {
    const bf16_t* __restrict__ Ap = s ? A2 : A1;
    const bf16_t* __restrict__ Wp = s ? W2t : W1t;
    for (int k0 = 0; k0 < K; k0 += 32) {
#pragma unroll
      for (int seg = 0; seg < 2; ++seg) {
        const int f = fbase + seg * 1024;
        const int r = f >> 6;              // tile row/col 0..127
        const int ke = (f & 63) >> 1;      // element offset within 32-elem k-slice
        size_t ar = row0 + r; if (ar >= (size_t)M) ar = M - 1;
        __builtin_amdgcn_global_load_lds(
            (const __attribute__((address_space(1))) void*)(Ap + ar * K + k0 + ke),
            (__attribute__((address_space(3))) void*)(Als + (f >> 1)), 16, 0, 0);
        __builtin_amdgcn_global_load_lds(
            (const __attribute__((address_space(1))) void*)(Wp + (size_t)(col0 + r) * K + k0 + ke),
            (__attribute__((address_space(3))) void*)(Bls + (f >> 1)), 16, 0, 0);
      }
      __syncthreads();
      const int aoff = (wr * 64 + (lane & 15)) * 32 + (lane >> 4) * 8;
      const int boff = (wc * 64 + (lane & 15)) * 32 + (lane >> 4) * 8;
      bf16x8 af[4], bfr[4];
#pragma unroll
      for (int i = 0; i < 4; ++i) {
        af[i] = *(const bf16x8*)(Als + aoff + i * 16 * 32);
        bfr[i] = *(const bf16x8*)(Bls + boff + i * 16 * 32);
      }
#pragma unroll
      for (int mi = 0; mi < 4; ++mi)
#pragma unroll
        for (int ni = 0; ni < 4; ++ni)
          acc[mi][ni] = __builtin_amdgcn_mfma_f32_16x16x32_bf16(af[mi], bfr[ni], acc[mi][ni], 0, 0, 0);
      __syncthreads();
    }
  }

  const int crow = wr * 64 + (lane >> 4) * 4;
  int ccol = col0 + wc * 64 + (lane & 15);
  bf16_t* Co = C;
  int stride = N;
  bool useBias = BIAS;
  if (SPLIT) {
    const int half = N >> 1;
    stride = half;
    if (col0 >= half) { Co = C2; ccol -= half; useBias = false; }
  }
#pragma unroll
  for (int mi = 0; mi < 4; ++mi) {
#pragma unroll
    for (int j = 0; j < 4; ++j) {
      size_t r = row0 + crow + mi * 16 + j;
      if (r < (size_t)M) {
#pragma unroll
        for (int ni = 0; ni < 4; ++ni) {
          float v = acc[mi][ni][j];
          if (BIAS) { if (useBias) v += bias[ccol + ni * 16]; }
          if (RELU) v = fmaxf(v, 0.f);
          Co[r * stride + ccol + ni * 16] = f2bf(v);
        }
      }
    }
  }
}

// ---------------- decode: 16 lanes/label, 16B loads ----------------
__global__ void decode16_k(const int* __restrict__ ls, const int* __restrict__ ld,
                           const bf16_t* __restrict__ zu, const bf16_t* __restrict__ zi,
                           float* __restrict__ out, int L) {
  long long gid = (long long)blockIdx.x * blockDim.x + threadIdx.x;
  int w = (int)(gid >> 4);
  int l = (int)(gid & 15);
  if (w >= L) return;
  int su = ls[w], si = ld[w];
  uint4 a = *(const uint4*)(zu + (size_t)su * OO + l * 8);
  uint4 b = *(const uint4*)(zi + (size_t)si * OO + l * 8);
  const unsigned* pa = (const unsigned*)&a;
  const unsigned* pb = (const unsigned*)&b;
  float sum = 0.f;
#pragma unroll
  for (int i = 0; i < 4; ++i) {
    union { unsigned v; float f; } la, ha, lb, hb;
    la.v = pa[i] << 16;        ha.v = pa[i] & 0xffff0000u;
    lb.v = pb[i] << 16;        hb.v = pb[i] & 0xffff0000u;
    sum += la.f * lb.f + ha.f * hb.f;
  }
#pragma unroll
  for (int m = 1; m < 16; m <<= 1) sum += __shfl_xor(sum, m);
  if (l == 0) out[w] = sum;
}

// ---------------------------------------------------------------------------
extern "C" void kernel_launch(void* const* d_in, const int* in_sizes, int n_in,
                              void* d_out, int out_size, void* d_ws, size_t ws_size,
                              hipStream_t stream) {
  const float* x_user = (const float*)d_in[0];
  const float* x_item = (const float*)d_in[1];
  const int* edge_src = (const int*)d_in[2];
  const int* edge_dst = (const int*)d_in[3];
  const int* lbl_src  = (const int*)d_in[4];
  const int* lbl_dst  = (const int*)d_in[5];
  const float* wl1_ui = (const float*)d_in[6];
  const float* wr1_ui = (const float*)d_in[7];
  const float* b1_ui  = (const float*)d_in[8];
  const float* wl1_iu = (const float*)d_in[9];
  const float* wr1_iu = (const float*)d_in[10];
  const float* b1_iu  = (const float*)d_in[11];
  const float* wl2_ui = (const float*)d_in[12];
  const float* wr2_ui = (const float*)d_in[13];
  const float* b2_ui  = (const float*)d_in[14];
  const float* wl2_iu = (const float*)d_in[15];
  const float* wr2_iu = (const float*)d_in[16];
  const float* b2_iu  = (const float*)d_in[17];

  const int NU = in_sizes[0] / DD;
  const int NI = in_sizes[1] / DD;
  const int E  = in_sizes[2];
  const int L  = in_sizes[4];
  const int nb_i = (NI + 1023) / 1024, nb_u = (NU + 1023) / 1024;
  const int Wi = (NI + NBI - 1) / NBI;   // bucket width (<=320 for LDS cur)
  const int Wu = (NU + NBU - 1) / NBU;
  const int nEB = (E + 4095) / 4096;

  // ---- workspace layout ----
  size_t off = 0;
  auto take = [&](size_t bytes) { size_t o = off; off = (off + bytes + 255) & ~(size_t)255; return o; };
  char* base = (char*)d_ws;
  int* deg_i = (int*)(base + take(((size_t)NI + NU + NBI + NBU) * 4));
  int* deg_u  = deg_i + NI;
  int* hist_i = deg_u + NU;
  int* hist_u = hist_i + NBI;
  size_t zeroB = ((size_t)NI + NU + NBI + NBU) * 4;
  int* row_i = (int*)(base + take((size_t)(NI + 1) * 4));
  int* row_u = (int*)(base + take((size_t)(NU + 1) * 4));
  int* part_i = (int*)(base + take((size_t)nb_i * 4));
  int* part_u = (int*)(base + take((size_t)nb_u * 4));
  int* off_i = (int*)(base + take((size_t)NBI * 4));
  int* off_u = (int*)(base + take((size_t)NBU * 4));
  int* cur_bi = (int*)(base + take((size_t)NBI * 4));
  int* cur_bu = (int*)(base + take((size_t)NBU * 4));
  int* csr_i = (int*)(base + take((size_t)E * 4));
  int* csr_u = (int*)(base + take((size_t)E * 4));
  unsigned int* ebuf_i = (unsigned int*)(base + take((size_t)E * 4));
  unsigned int* ebuf_u = (unsigned int*)(base + take((size_t)E * 4));
  bf16_t* pool = (bf16_t*)(base + take((size_t)(NI + NU) * HH * 2));
  bf16_t* agg_i   = pool;                              // NI*DD
  bf16_t* agg_u   = agg_i + (size_t)NI * DD;           // NU*DD
  bf16_t* xb_item = agg_u + (size_t)NU * DD;           // NI*DD
  bf16_t* xb_user = xb_item + (size_t)NI * DD;         // NU*DD
  bf16_t* t_user  = pool;                              // NU*OO
  bf16_t* t_item  = t_user + (size_t)NU * OO;          // NI*OO
  bf16_t* h_item = (bf16_t*)(base + take((size_t)(NI + NU) * HH * 2));
  bf16_t* h_user = h_item + (size_t)NI * HH;
  bf16_t* z_item = (bf16_t*)(base + take((size_t)(NI + NU) * OO * 2));
  bf16_t* z_user = z_item + (size_t)NI * OO;
  bf16_t* Wt1[4];
  for (int w = 0; w < 4; ++w) Wt1[w] = (bf16_t*)(base + take((size_t)HH * DD * 2));
  bf16_t* Wcat_item = (bf16_t*)(base + take((size_t)2 * OO * HH * 2));
  bf16_t* Wcat_user = (bf16_t*)(base + take((size_t)2 * OO * HH * 2));
  size_t need = off;

  float* out = (float*)d_out;
  if (ws_size < need || Wi > 320 || Wu > 320) {
    probe_k<<<(L + 255) / 256, 256, 0, stream>>>(out, L, (float)(ws_size >> 20));
    return;
  }

  // ---- CSR build ----
  hipMemsetAsync(deg_i, 0, zeroB, stream);
  degree_hist_k<<<nEB, 256, 0, stream>>>(edge_src, edge_dst, deg_u, deg_i, hist_u, hist_i, E, Wi, Wu);
  scan1_k<<<nb_i, 256, 0, stream>>>(deg_i, row_i, part_i, NI);
  scan1_k<<<nb_u, 256, 0, stream>>>(deg_u, row_u, part_u, NU);
  scan2_k<<<1, 1024, 0, stream>>>(part_i, nb_i);
  scan2_k<<<1, 1024, 0, stream>>>(part_u, nb_u);
  scan3_k<<<(NI + 255) / 256, 256, 0, stream>>>(row_i, part_i, NI, E);
  scan3_k<<<(NU + 255) / 256, 256, 0, stream>>>(row_u, part_u, NU, E);
  scan_small_pair_k<<<2, 512, 0, stream>>>(hist_i, off_i, cur_bi, hist_u, off_u, cur_bu);
  bucket_append_k<<<nEB, 256, 0, stream>>>(edge_src, edge_dst, E, Wi, Wu, cur_bi, cur_bu, ebuf_i, ebuf_u);
  bucket_fill_k<<<NBI, 256, 0, stream>>>(ebuf_i, off_i, cur_bi, row_i, csr_i, NI, Wi);
  bucket_fill_k<<<NBU, 256, 0, stream>>>(ebuf_u, off_u, cur_bu, row_u, csr_u, NU, Wu);

  // ---- dtype prep ----
  cvt_bf16_k<<<(NI * DD / 4 + 255) / 256, 256, 0, stream>>>(x_item, xb_item, NI * DD / 4);
  cvt_bf16_k<<<(NU * DD / 4 + 255) / 256, 256, 0, stream>>>(x_user, xb_user, NU * DD / 4);
  {
    WBatch w1;
    w1.in[0] = wl1_ui; w1.out[0] = Wt1[0];
    w1.in[1] = wr1_ui; w1.out[1] = Wt1[1];
    w1.in[2] = wl1_iu; w1.out[2] = Wt1[2];
    w1.in[3] = wr1_iu; w1.out[3] = Wt1[3];
    dim3 g1(HH / 32, DD / 32, 4);  // [D,H] -> [H,D]
    twconv_batch_k<<<g1, 256, 0, stream>>>(w1, DD, HH);
    WBatch w2;
    w2.in[0] = wr2_ui; w2.out[0] = Wcat_item;
    w2.in[1] = wl2_iu; w2.out[1] = Wcat_item + (size_t)OO * HH;
    w2.in[2] = wr2_iu; w2.out[2] = Wcat_user;
    w2.in[3] = wl2_ui; w2.out[3] = Wcat_user + (size_t)OO * HH;
    dim3 g2(OO / 32, HH / 32, 4);  // [H,O] -> [O,H]
    twconv_batch_k<<<g2, 256, 0, stream>>>(w2, HH, OO);
  }

  // ---- layer 1: gather-mean + dual GEMM ----
  gather_mean16_k<false><<<(NI * 64 + 255) / 256, 256, 0, stream>>>(row_i, csr_i, xb_user, agg_i, NI);
  gather_mean16_k<false><<<(NU * 64 + 255) / 256, 256, 0, stream>>>(row_u, csr_u, xb_item, agg_u, NU);
  {
    dim3 g(HH / 128, (NI + 127) / 128);
    mfma_gemm_k<true, true, true, false><<<g, 256, 0, stream>>>(
        NI, HH, DD, agg_i, xb_item, Wt1[0], Wt1[1], b1_ui, h_item, nullptr);
    dim3 g2(HH / 128, (NU + 127) / 128);
    mfma_gemm_k<true, true, true, false><<<g2, 256, 0, stream>>>(
        NU, HH, DD, agg_u, xb_user, Wt1[2], Wt1[3], b1_iu, h_user, nullptr);
  }

  // ---- layer 2 (re-associated, merged split GEMMs) ----
  {
    dim3 g(2, (NI + 127) / 128);
    mfma_gemm_k<false, false, true, true><<<g, 256, 0, stream>>>(
        NI, 2 * OO, HH, h_item, nullptr, Wcat_item, nullptr, b2_ui, z_item, t_item);
    dim3 g2(2, (NU + 127) / 128);
    mfma_gemm_k<false, false, true, true><<<g2, 256, 0, stream>>>(
        NU, 2 * OO, HH, h_user, nullptr, Wcat_user, nullptr, b2_iu, z_user, t_user);
  }
  gather_mean16_k<true><<<(NI * 64 + 255) / 256, 256, 0, stream>>>(row_i, csr_i, t_user, z_item, NI);
  gather_mean16_k<true><<<(NU * 64 + 255) / 256, 256, 0, stream>>>(row_u, csr_u, t_item, z_user, NU);

  // ---- decode ----
  decode16_k<<<(int)(((long long)L * 16 + 255) / 256), 256, 0, stream>>>(lbl_src, lbl_dst, z_user, z_item, out, L);
}

// Round 8
// 430.955 us; speedup vs baseline: 20.3526x; 1.1330x over previous
//
#include <hip/hip_runtime.h>

#define DD 128   // input feature dim D
#define HH 256   // hidden dim H
#define OO 128   // output dim O

// CSR bucket config
#define NBI 256
#define NBU 512

typedef unsigned short bf16_t;
typedef short bf16x8 __attribute__((ext_vector_type(8)));   // 8 bf16 = 4 VGPRs
typedef float f32x4 __attribute__((ext_vector_type(4)));

__device__ __forceinline__ float bf2f(bf16_t u) {
  union { unsigned int i; float f; } v; v.i = ((unsigned int)u) << 16; return v.f;
}
__device__ __forceinline__ bf16_t f2bf(float f) {
  union { float f; unsigned int i; } v; v.f = f;
  unsigned int r = v.i + 0x7FFFu + ((v.i >> 16) & 1u);  // RNE
  return (bf16_t)(r >> 16);
}

__device__ __forceinline__ void acc8(float* acc, uint4 u) {
  const unsigned* p = (const unsigned*)&u;
#pragma unroll
  for (int i = 0; i < 4; ++i) {
    union { unsigned v; float f; } lo, hi;
    lo.v = p[i] << 16;
    hi.v = p[i] & 0xffff0000u;
    acc[2 * i] += lo.f;
    acc[2 * i + 1] += hi.f;
  }
}
__device__ __forceinline__ void unpack8(float* o, uint4 u) {
  const unsigned* p = (const unsigned*)&u;
#pragma unroll
  for (int i = 0; i < 4; ++i) {
    union { unsigned v; float f; } lo, hi;
    lo.v = p[i] << 16;
    hi.v = p[i] & 0xffff0000u;
    o[2 * i] = lo.f;
    o[2 * i + 1] = hi.f;
  }
}
__device__ __forceinline__ uint4 pack8(const float* v) {
  uint4 o; unsigned* p = (unsigned*)&o;
#pragma unroll
  for (int i = 0; i < 4; ++i)
    p[i] = (unsigned)f2bf(v[2 * i]) | ((unsigned)f2bf(v[2 * i + 1]) << 16);
  return o;
}

// ---------------------------------------------------------------------------
__global__ void probe_k(float* __restrict__ out, int n, float v) {
  int i = blockIdx.x * blockDim.x + threadIdx.x;
  if (i < n) out[i] = v;
}

// ---------------- CSR build (bucketed, no per-node global atomics) ----------
// bucket histograms only: LDS counters + one global add per bucket per block
__global__ __launch_bounds__(256) void hist_k(
    const int* __restrict__ src, const int* __restrict__ dst,
    int* __restrict__ hist_u, int* __restrict__ hist_i,
    int E, int Wi, int Wu) {
  __shared__ int hi[NBI], hu[NBU];
  int tid = threadIdx.x;
  for (int t = tid; t < NBI; t += 256) hi[t] = 0;
  for (int t = tid; t < NBU; t += 256) hu[t] = 0;
  __syncthreads();
  int base = blockIdx.x * 4096;
#pragma unroll
  for (int j = 0; j < 16; ++j) {
    int e = base + tid + j * 256;
    if (e < E) {
      atomicAdd(&hi[dst[e] / Wi], 1);
      atomicAdd(&hu[src[e] / Wu], 1);
    }
  }
  __syncthreads();
  for (int t = tid; t < NBI; t += 256) if (hi[t]) atomicAdd(hist_i + t, hi[t]);
  for (int t = tid; t < NBU; t += 256) if (hu[t]) atomicAdd(hist_u + t, hu[t]);
}

// bucket-histogram exclusive scan for both sides (block 0: item, 1: user)
__global__ __launch_bounds__(512) void scan_small_pair_k(
    const int* __restrict__ hist_i, int* __restrict__ off_i, int* __restrict__ cur_i,
    const int* __restrict__ hist_u, int* __restrict__ off_u, int* __restrict__ cur_u) {
  __shared__ int lds[512];
  const int* hist = blockIdx.x ? hist_u : hist_i;
  int* off = blockIdx.x ? off_u : off_i;
  int* cur = blockIdx.x ? cur_u : cur_i;
  int n = blockIdx.x ? NBU : NBI;
  int t = threadIdx.x;
  int v = (t < n) ? hist[t] : 0;
  lds[t] = v; __syncthreads();
  for (int o = 1; o < 512; o <<= 1) {
    int tv = (t >= o) ? lds[t - o] : 0;
    __syncthreads(); lds[t] += tv; __syncthreads();
  }
  if (t < n) { int e = lds[t] - v; off[t] = e; cur[t] = e; }
}

// block-aggregated bucket append: per block, reserve chunk per bucket with one
// global atomic, then write packed entries ((local<<24)|other) contiguously.
__global__ __launch_bounds__(256) void bucket_append_k(
    const int* __restrict__ src, const int* __restrict__ dst, int E, int Wi, int Wu,
    int* __restrict__ cur_bi, int* __restrict__ cur_bu,
    unsigned int* __restrict__ ebuf_i, unsigned int* __restrict__ ebuf_u) {
  __shared__ int bi[NBI], bu[NBU];
  __shared__ uint2 es[4096];
  int tid = threadIdx.x;
  int base = blockIdx.x * 4096;
  int n = E - base; if (n > 4096) n = 4096;
  for (int t = tid; t < NBI; t += 256) bi[t] = 0;
  for (int t = tid; t < NBU; t += 256) bu[t] = 0;
  __syncthreads();
#pragma unroll
  for (int j = 0; j < 16; ++j) {
    int idx = tid + j * 256;
    if (idx < n) {
      int s = src[base + idx], d = dst[base + idx];
      es[idx] = make_uint2((unsigned)s, (unsigned)d);
      atomicAdd(&bi[d / Wi], 1);
      atomicAdd(&bu[s / Wu], 1);
    }
  }
  __syncthreads();
  for (int t = tid; t < NBI; t += 256) { int c = bi[t]; bi[t] = c ? atomicAdd(cur_bi + t, c) : 0; }
  for (int t = tid; t < NBU; t += 256) { int c = bu[t]; bu[t] = c ? atomicAdd(cur_bu + t, c) : 0; }
  __syncthreads();
#pragma unroll
  for (int j = 0; j < 16; ++j) {
    int idx = tid + j * 256;
    if (idx < n) {
      int s = (int)es[idx].x, d = (int)es[idx].y;
      int bI = d / Wi, bU = s / Wu;
      int pI = atomicAdd(&bi[bI], 1);
      int pU = atomicAdd(&bu[bU], 1);
      ebuf_i[pI] = ((unsigned)(d - bI * Wi) << 24) | (unsigned)s;
      ebuf_u[pU] = ((unsigned)(s - bU * Wu) << 24) | (unsigned)d;
    }
  }
}

// per-bucket: LDS dst-histogram -> wave-scan -> row[] + csr fill.
// Produces row pointers AND csr in one pass; no global per-node atomics.
__global__ __launch_bounds__(256) void bucket_fill2_k(
    const unsigned int* __restrict__ ebuf, const int* __restrict__ off,
    const int* __restrict__ endc, int* __restrict__ row,
    int* __restrict__ csr, int n, int W, int E) {
  int b = blockIdx.x;
  int d0 = b * W; if (d0 >= n) return;
  int cnt = n - d0; if (cnt > W) cnt = W;
  __shared__ int hist[320];
  __shared__ int cur[320];
  int tid = threadIdx.x;
  for (int t = tid; t < cnt; t += 256) hist[t] = 0;
  __syncthreads();
  int beg = off[b], e_end = endc[b];
  for (int e = beg + tid; e < e_end; e += 256)
    atomicAdd(&hist[ebuf[e] >> 24], 1);
  __syncthreads();
  if (tid < 64) {
    int lane = tid;
    int carry = beg;                       // global CSR base of this bucket
    int nc = (cnt + 63) >> 6;
    for (int c = 0; c < nc; ++c) {
      int idx = (c << 6) + lane;
      int v = (idx < cnt) ? hist[idx] : 0;
      int x = v;
#pragma unroll
      for (int o = 1; o < 64; o <<= 1) { int t = __shfl_up(x, o); if (lane >= o) x += t; }
      if (idx < cnt) { int g = carry + x - v; row[d0 + idx] = g; cur[idx] = g; }
      carry += __shfl(x, 63);
    }
  }
  if (tid == 0 && d0 + cnt == n) row[n] = E;
  __syncthreads();
  for (int e = beg + tid; e < e_end; e += 256) {
    unsigned v = ebuf[e];
    int slot = atomicAdd(&cur[v >> 24], 1);
    csr[slot] = (int)(v & 0xFFFFFFu);
  }
}

// ---------------- dtype prep ----------------
__global__ void cvt_bf16_k(const float* __restrict__ in, bf16_t* __restrict__ out, int n4) {
  int i = blockIdx.x * blockDim.x + threadIdx.x;
  if (i < n4) {
    float4 v = ((const float4*)in)[i];
    ushort4 o; o.x = f2bf(v.x); o.y = f2bf(v.y); o.z = f2bf(v.z); o.w = f2bf(v.w);
    ((ushort4*)out)[i] = o;
  }
}

struct WBatch { const float* in[4]; bf16_t* out[4]; };
__global__ void twconv_batch_k(WBatch wb, int K, int N) {
  const float* __restrict__ in = wb.in[blockIdx.z];
  bf16_t* __restrict__ out = wb.out[blockIdx.z];
  __shared__ float t[32][33];
  int bx = blockIdx.x * 32, by = blockIdx.y * 32;
  int tx = threadIdx.x & 31, ty = threadIdx.x >> 5;  // 32x8
#pragma unroll
  for (int j = 0; j < 32; j += 8)
    t[ty + j][tx] = in[(size_t)(by + ty + j) * N + bx + tx];
  __syncthreads();
#pragma unroll
  for (int j = 0; j < 32; j += 8)
    out[(size_t)(bx + ty + j) * K + by + tx] = f2bf(t[tx][ty + j]);
}

// ---------------- gather-mean, D=128, 16 lanes/row, 4 rows in flight ----------
template<bool ADD>
__global__ void gather_mean16_k(const int* __restrict__ row, const int* __restrict__ csr,
                                const bf16_t* __restrict__ X, bf16_t* __restrict__ agg, int n) {
  int node = (int)(((long long)blockIdx.x * blockDim.x + threadIdx.x) >> 6);
  int lane = threadIdx.x & 63;
  if (node >= n) return;
  const int g = lane >> 4;      // group 0..3 (one neighbor row each)
  const int l = lane & 15;      // 16 lanes x 16B = 256B row
  int beg = row[node], end = row[node + 1];
  float acc[8] = {};
  for (int j0 = beg; j0 < end; j0 += 64) {
    int cnt = min(64, end - j0);
    int my = (lane < cnt) ? csr[j0 + lane] : 0;
    for (int k = 0; k < cnt; k += 4) {
      int idx = __shfl(my, k + g);
      if (k + g < cnt) {
        uint4 u = *(const uint4*)(X + (size_t)idx * 128 + l * 8);
        acc8(acc, u);
      }
    }
  }
#pragma unroll
  for (int m = 16; m < 64; m <<= 1)
#pragma unroll
    for (int i = 0; i < 8; ++i) acc[i] += __shfl_xor(acc[i], m);
  if (g == 0) {
    float inv = (end > beg) ? 1.0f / (float)(end - beg) : 0.0f;
    float v[8];
    if (ADD) {
      uint4 z = *(const uint4*)(agg + (size_t)node * 128 + l * 8);
      float zb[8]; unpack8(zb, z);
#pragma unroll
      for (int i = 0; i < 8; ++i) v[i] = acc[i] * inv + zb[i];
    } else {
#pragma unroll
      for (int i = 0; i < 8; ++i) v[i] = acc[i] * inv;
    }
    *(uint4*)(agg + (size_t)node * 128 + l * 8) = pack8(v);
  }
}

// ---------------- MFMA GEMM ----------------
template<bool RELU, bool DUAL, bool BIAS, bool SPLIT>
__global__ __launch_bounds__(256) void mfma_gemm_k(
    int M, int N, int K,
    const bf16_t* __restrict__ A1, const bf16_t* __restrict__ A2,
    const bf16_t* __restrict__ W1t, const bf16_t* __restrict__ W2t,
    const float* __restrict__ bias, bf16_t* __restrict__ C, bf16_t* __restrict__ C2) {
  __shared__ __align__(16) bf16_t Als[128 * 32];  // [row][k] 64B rows
  __shared__ __align__(16) bf16_t Bls[128 * 32];  // [col][k]
  const int tid = threadIdx.x;
  const int wave = tid >> 6, lane = tid & 63;
  const int wr = wave >> 1, wc = wave & 1;
  const size_t row0 = (size_t)blockIdx.y * 128;
  const int col0 = blockIdx.x * 128;

  f32x4 acc[4][4] = {};

  const int fbase = wave * 2048 + lane * 16;  // byte offset of this lane's 16B slot

  for (int s = 0; s < (DUAL ? 2 : 1); ++s) {
    const bf16_t* __restrict__ Ap = s ? A2 : A1;
    const bf16_t* __restrict__ Wp = s ? W2t : W1t;
    for (int k0 = 0; k0 < K; k0 += 32) {
#pragma unroll
      for (int seg = 0; seg < 2; ++seg) {
        const int f = fbase + seg * 1024;
        const int r = f >> 6;              // tile row/col 0..127
        const int ke = (f & 63) >> 1;      // element offset within 32-elem k-slice
        size_t ar = row0 + r; if (ar >= (size_t)M) ar = M - 1;
        __builtin_amdgcn_global_load_lds(
            (const __attribute__((address_space(1))) void*)(Ap + ar * K + k0 + ke),
            (__attribute__((address_space(3))) void*)(Als + (f >> 1)), 16, 0, 0);
        __builtin_amdgcn_global_load_lds(
            (const __attribute__((address_space(1))) void*)(Wp + (size_t)(col0 + r) * K + k0 + ke),
            (__attribute__((address_space(3))) void*)(Bls + (f >> 1)), 16, 0, 0);
      }
      __syncthreads();
      const int aoff = (wr * 64 + (lane & 15)) * 32 + (lane >> 4) * 8;
      const int boff = (wc * 64 + (lane & 15)) * 32 + (lane >> 4) * 8;
      bf16x8 af[4], bfr[4];
#pragma unroll
      for (int i = 0; i < 4; ++i) {
        af[i] = *(const bf16x8*)(Als + aoff + i * 16 * 32);
        bfr[i] = *(const bf16x8*)(Bls + boff + i * 16 * 32);
      }
#pragma unroll
      for (int mi = 0; mi < 4; ++mi)
#pragma unroll
        for (int ni = 0; ni < 4; ++ni)
          acc[mi][ni] = __builtin_amdgcn_mfma_f32_16x16x32_bf16(af[mi], bfr[ni], acc[mi][ni], 0, 0, 0);
      __syncthreads();
    }
  }

  const int crow = wr * 64 + (lane >> 4) * 4;
  int ccol = col0 + wc * 64 + (lane & 15);
  bf16_t* Co = C;
  int stride = N;
  bool useBias = BIAS;
  if (SPLIT) {
    const int half = N >> 1;
    stride = half;
    if (col0 >= half) { Co = C2; ccol -= half; useBias = false; }
  }
#pragma unroll
  for (int mi = 0; mi < 4; ++mi) {
#pragma unroll
    for (int j = 0; j < 4; ++j) {
      size_t r = row0 + crow + mi * 16 + j;
      if (r < (size_t)M) {
#pragma unroll
        for (int ni = 0; ni < 4; ++ni) {
          float v = acc[mi][ni][j];
          if (BIAS) { if (useBias) v += bias[ccol + ni * 16]; }
          if (RELU) v = fmaxf(v, 0.f);
          Co[r * stride + ccol + ni * 16] = f2bf(v);
        }
      }
    }
  }
}

// ---------------- decode: 16 lanes/label, 16B loads ----------------
__global__ void decode16_k(const int* __restrict__ ls, const int* __restrict__ ld,
                           const bf16_t* __restrict__ zu, const bf16_t* __restrict__ zi,
                           float* __restrict__ out, int L) {
  long long gid = (long long)blockIdx.x * blockDim.x + threadIdx.x;
  int w = (int)(gid >> 4);
  int l = (int)(gid & 15);
  if (w >= L) return;
  int su = ls[w], si = ld[w];
  uint4 a = *(const uint4*)(zu + (size_t)su * OO + l * 8);
  uint4 b = *(const uint4*)(zi + (size_t)si * OO + l * 8);
  const unsigned* pa = (const unsigned*)&a;
  const unsigned* pb = (const unsigned*)&b;
  float sum = 0.f;
#pragma unroll
  for (int i = 0; i < 4; ++i) {
    union { unsigned v; float f; } la, ha, lb, hb;
    la.v = pa[i] << 16;        ha.v = pa[i] & 0xffff0000u;
    lb.v = pb[i] << 16;        hb.v = pb[i] & 0xffff0000u;
    sum += la.f * lb.f + ha.f * hb.f;
  }
#pragma unroll
  for (int m = 1; m < 16; m <<= 1) sum += __shfl_xor(sum, m);
  if (l == 0) out[w] = sum;
}

// ---------------------------------------------------------------------------
extern "C" void kernel_launch(void* const* d_in, const int* in_sizes, int n_in,
                              void* d_out, int out_size, void* d_ws, size_t ws_size,
                              hipStream_t stream) {
  const float* x_user = (const float*)d_in[0];
  const float* x_item = (const float*)d_in[1];
  const int* edge_src = (const int*)d_in[2];
  const int* edge_dst = (const int*)d_in[3];
  const int* lbl_src  = (const int*)d_in[4];
  const int* lbl_dst  = (const int*)d_in[5];
  const float* wl1_ui = (const float*)d_in[6];
  const float* wr1_ui = (const float*)d_in[7];
  const float* b1_ui  = (const float*)d_in[8];
  const float* wl1_iu = (const float*)d_in[9];
  const float* wr1_iu = (const float*)d_in[10];
  const float* b1_iu  = (const float*)d_in[11];
  const float* wl2_ui = (const float*)d_in[12];
  const float* wr2_ui = (const float*)d_in[13];
  const float* b2_ui  = (const float*)d_in[14];
  const float* wl2_iu = (const float*)d_in[15];
  const float* wr2_iu = (const float*)d_in[16];
  const float* b2_iu  = (const float*)d_in[17];

  const int NU = in_sizes[0] / DD;
  const int NI = in_sizes[1] / DD;
  const int E  = in_sizes[2];
  const int L  = in_sizes[4];
  const int Wi = (NI + NBI - 1) / NBI;   // bucket width (<=320 for LDS arrays)
  const int Wu = (NU + NBU - 1) / NBU;
  const int nEB = (E + 4095) / 4096;

  // ---- workspace layout ----
  size_t off = 0;
  auto take = [&](size_t bytes) { size_t o = off; off = (off + bytes + 255) & ~(size_t)255; return o; };
  char* base = (char*)d_ws;
  int* hist_i = (int*)(base + take(((size_t)NBI + NBU) * 4));  // zeroed together
  int* hist_u = hist_i + NBI;
  size_t zeroB = ((size_t)NBI + NBU) * 4;
  int* row_i = (int*)(base + take((size_t)(NI + 1) * 4));
  int* row_u = (int*)(base + take((size_t)(NU + 1) * 4));
  int* off_i = (int*)(base + take((size_t)NBI * 4));
  int* off_u = (int*)(base + take((size_t)NBU * 4));
  int* cur_bi = (int*)(base + take((size_t)NBI * 4));
  int* cur_bu = (int*)(base + take((size_t)NBU * 4));
  int* csr_i = (int*)(base + take((size_t)E * 4));
  int* csr_u = (int*)(base + take((size_t)E * 4));
  unsigned int* ebuf_i = (unsigned int*)(base + take((size_t)E * 4));
  unsigned int* ebuf_u = (unsigned int*)(base + take((size_t)E * 4));
  bf16_t* pool = (bf16_t*)(base + take((size_t)(NI + NU) * HH * 2));
  bf16_t* agg_i   = pool;                              // NI*DD
  bf16_t* agg_u   = agg_i + (size_t)NI * DD;           // NU*DD
  bf16_t* xb_item = agg_u + (size_t)NU * DD;           // NI*DD
  bf16_t* xb_user = xb_item + (size_t)NI * DD;         // NU*DD
  bf16_t* t_user  = pool;                              // NU*OO
  bf16_t* t_item  = t_user + (size_t)NU * OO;          // NI*OO
  bf16_t* h_item = (bf16_t*)(base + take((size_t)(NI + NU) * HH * 2));
  bf16_t* h_user = h_item + (size_t)NI * HH;
  bf16_t* z_item = (bf16_t*)(base + take((size_t)(NI + NU) * OO * 2));
  bf16_t* z_user = z_item + (size_t)NI * OO;
  bf16_t* Wt1[4];
  for (int w = 0; w < 4; ++w) Wt1[w] = (bf16_t*)(base + take((size_t)HH * DD * 2));
  bf16_t* Wcat_item = (bf16_t*)(base + take((size_t)2 * OO * HH * 2));
  bf16_t* Wcat_user = (bf16_t*)(base + take((size_t)2 * OO * HH * 2));
  size_t need = off;

  float* out = (float*)d_out;
  if (ws_size < need || Wi > 320 || Wu > 320) {
    probe_k<<<(L + 255) / 256, 256, 0, stream>>>(out, L, (float)(ws_size >> 20));
    return;
  }

  // ---- CSR build (bucketed; no per-node global atomics, no node scans) ----
  hipMemsetAsync(hist_i, 0, zeroB, stream);
  hist_k<<<nEB, 256, 0, stream>>>(edge_src, edge_dst, hist_u, hist_i, E, Wi, Wu);
  scan_small_pair_k<<<2, 512, 0, stream>>>(hist_i, off_i, cur_bi, hist_u, off_u, cur_bu);
  bucket_append_k<<<nEB, 256, 0, stream>>>(edge_src, edge_dst, E, Wi, Wu, cur_bi, cur_bu, ebuf_i, ebuf_u);
  bucket_fill2_k<<<NBI, 256, 0, stream>>>(ebuf_i, off_i, cur_bi, row_i, csr_i, NI, Wi, E);
  bucket_fill2_k<<<NBU, 256, 0, stream>>>(ebuf_u, off_u, cur_bu, row_u, csr_u, NU, Wu, E);

  // ---- dtype prep ----
  cvt_bf16_k<<<(NI * DD / 4 + 255) / 256, 256, 0, stream>>>(x_item, xb_item, NI * DD / 4);
  cvt_bf16_k<<<(NU * DD / 4 + 255) / 256, 256, 0, stream>>>(x_user, xb_user, NU * DD / 4);
  {
    WBatch w1;
    w1.in[0] = wl1_ui; w1.out[0] = Wt1[0];
    w1.in[1] = wr1_ui; w1.out[1] = Wt1[1];
    w1.in[2] = wl1_iu; w1.out[2] = Wt1[2];
    w1.in[3] = wr1_iu; w1.out[3] = Wt1[3];
    dim3 g1(HH / 32, DD / 32, 4);  // [D,H] -> [H,D]
    twconv_batch_k<<<g1, 256, 0, stream>>>(w1, DD, HH);
    WBatch w2;
    w2.in[0] = wr2_ui; w2.out[0] = Wcat_item;
    w2.in[1] = wl2_iu; w2.out[1] = Wcat_item + (size_t)OO * HH;
    w2.in[2] = wr2_iu; w2.out[2] = Wcat_user;
    w2.in[3] = wl2_ui; w2.out[3] = Wcat_user + (size_t)OO * HH;
    dim3 g2(OO / 32, HH / 32, 4);  // [H,O] -> [O,H]
    twconv_batch_k<<<g2, 256, 0, stream>>>(w2, HH, OO);
  }

  // ---- layer 1: gather-mean + dual GEMM ----
  gather_mean16_k<false><<<(NI * 64 + 255) / 256, 256, 0, stream>>>(row_i, csr_i, xb_user, agg_i, NI);
  gather_mean16_k<false><<<(NU * 64 + 255) / 256, 256, 0, stream>>>(row_u, csr_u, xb_item, agg_u, NU);
  {
    dim3 g(HH / 128, (NI + 127) / 128);
    mfma_gemm_k<true, true, true, false><<<g, 256, 0, stream>>>(
        NI, HH, DD, agg_i, xb_item, Wt1[0], Wt1[1], b1_ui, h_item, nullptr);
    dim3 g2(HH / 128, (NU + 127) / 128);
    mfma_gemm_k<true, true, true, false><<<g2, 256, 0, stream>>>(
        NU, HH, DD, agg_u, xb_user, Wt1[2], Wt1[3], b1_iu, h_user, nullptr);
  }

  // ---- layer 2 (re-associated, merged split GEMMs) ----
  {
    dim3 g(2, (NI + 127) / 128);
    mfma_gemm_k<false, false, true, true><<<g, 256, 0, stream>>>(
        NI, 2 * OO, HH, h_item, nullptr, Wcat_item, nullptr, b2_ui, z_item, t_item);
    dim3 g2(2, (NU + 127) / 128);
    mfma_gemm_k<false, false, true, true><<<g2, 256, 0, stream>>>(
        NU, 2 * OO, HH, h_user, nullptr, Wcat_user, nullptr, b2_iu, z_user, t_user);
  }
  gather_mean16_k<true><<<(NI * 64 + 255) / 256, 256, 0, stream>>>(row_i, csr_i, t_user, z_item, NI);
  gather_mean16_k<true><<<(NU * 64 + 255) / 256, 256, 0, stream>>>(row_u, csr_u, t_item, z_user, NU);

  // ---- decode ----
  decode16_k<<<(int)(((long long)L * 16 + 255) / 256), 256, 0, stream>>>(lbl_src, lbl_dst, z_user, z_item, out, L);
}

// Round 9
// 395.933 us; speedup vs baseline: 22.1529x; 1.0885x over previous
//
#include <hip/hip_runtime.h>

#define DD 128   // input feature dim D
#define HH 256   // hidden dim H
#define OO 128   // output dim O

// CSR bucket config
#define NBI 256
#define NBU 512

typedef unsigned short bf16_t;
typedef short bf16x8 __attribute__((ext_vector_type(8)));   // 8 bf16 = 4 VGPRs
typedef float f32x4 __attribute__((ext_vector_type(4)));

__device__ __forceinline__ float bf2f(bf16_t u) {
  union { unsigned int i; float f; } v; v.i = ((unsigned int)u) << 16; return v.f;
}
__device__ __forceinline__ bf16_t f2bf(float f) {
  union { float f; unsigned int i; } v; v.f = f;
  unsigned int r = v.i + 0x7FFFu + ((v.i >> 16) & 1u);  // RNE
  return (bf16_t)(r >> 16);
}

__device__ __forceinline__ void acc8(float* acc, uint4 u) {
  const unsigned* p = (const unsigned*)&u;
#pragma unroll
  for (int i = 0; i < 4; ++i) {
    union { unsigned v; float f; } lo, hi;
    lo.v = p[i] << 16;
    hi.v = p[i] & 0xffff0000u;
    acc[2 * i] += lo.f;
    acc[2 * i + 1] += hi.f;
  }
}
__device__ __forceinline__ void unpack8(float* o, uint4 u) {
  const unsigned* p = (const unsigned*)&u;
#pragma unroll
  for (int i = 0; i < 4; ++i) {
    union { unsigned v; float f; } lo, hi;
    lo.v = p[i] << 16;
    hi.v = p[i] & 0xffff0000u;
    o[2 * i] = lo.f;
    o[2 * i + 1] = hi.f;
  }
}
__device__ __forceinline__ uint4 pack8(const float* v) {
  uint4 o; unsigned* p = (unsigned*)&o;
#pragma unroll
  for (int i = 0; i < 4; ++i)
    p[i] = (unsigned)f2bf(v[2 * i]) | ((unsigned)f2bf(v[2 * i + 1]) << 16);
  return o;
}

// ---------------------------------------------------------------------------
__global__ void probe_k(float* __restrict__ out, int n, float v) {
  int i = blockIdx.x * blockDim.x + threadIdx.x;
  if (i < n) out[i] = v;
}

// ---------------- CSR build (bucketed, no per-node global atomics) ----------
__global__ __launch_bounds__(256) void hist_k(
    const int* __restrict__ src, const int* __restrict__ dst,
    int* __restrict__ hist_u, int* __restrict__ hist_i,
    int E, int Wi, int Wu) {
  __shared__ int hi[NBI], hu[NBU];
  int tid = threadIdx.x;
  for (int t = tid; t < NBI; t += 256) hi[t] = 0;
  for (int t = tid; t < NBU; t += 256) hu[t] = 0;
  __syncthreads();
  int base = blockIdx.x * 4096;
#pragma unroll
  for (int j = 0; j < 16; ++j) {
    int e = base + tid + j * 256;
    if (e < E) {
      atomicAdd(&hi[dst[e] / Wi], 1);
      atomicAdd(&hu[src[e] / Wu], 1);
    }
  }
  __syncthreads();
  for (int t = tid; t < NBI; t += 256) if (hi[t]) atomicAdd(hist_i + t, hi[t]);
  for (int t = tid; t < NBU; t += 256) if (hu[t]) atomicAdd(hist_u + t, hu[t]);
}

__global__ __launch_bounds__(512) void scan_small_pair_k(
    const int* __restrict__ hist_i, int* __restrict__ off_i, int* __restrict__ cur_i,
    const int* __restrict__ hist_u, int* __restrict__ off_u, int* __restrict__ cur_u) {
  __shared__ int lds[512];
  const int* hist = blockIdx.x ? hist_u : hist_i;
  int* off = blockIdx.x ? off_u : off_i;
  int* cur = blockIdx.x ? cur_u : cur_i;
  int n = blockIdx.x ? NBU : NBI;
  int t = threadIdx.x;
  int v = (t < n) ? hist[t] : 0;
  lds[t] = v; __syncthreads();
  for (int o = 1; o < 512; o <<= 1) {
    int tv = (t >= o) ? lds[t - o] : 0;
    __syncthreads(); lds[t] += tv; __syncthreads();
  }
  if (t < n) { int e = lds[t] - v; off[t] = e; cur[t] = e; }
}

__global__ __launch_bounds__(256) void bucket_append_k(
    const int* __restrict__ src, const int* __restrict__ dst, int E, int Wi, int Wu,
    int* __restrict__ cur_bi, int* __restrict__ cur_bu,
    unsigned int* __restrict__ ebuf_i, unsigned int* __restrict__ ebuf_u) {
  __shared__ int bi[NBI], bu[NBU];
  __shared__ uint2 es[4096];
  int tid = threadIdx.x;
  int base = blockIdx.x * 4096;
  int n = E - base; if (n > 4096) n = 4096;
  for (int t = tid; t < NBI; t += 256) bi[t] = 0;
  for (int t = tid; t < NBU; t += 256) bu[t] = 0;
  __syncthreads();
#pragma unroll
  for (int j = 0; j < 16; ++j) {
    int idx = tid + j * 256;
    if (idx < n) {
      int s = src[base + idx], d = dst[base + idx];
      es[idx] = make_uint2((unsigned)s, (unsigned)d);
      atomicAdd(&bi[d / Wi], 1);
      atomicAdd(&bu[s / Wu], 1);
    }
  }
  __syncthreads();
  for (int t = tid; t < NBI; t += 256) { int c = bi[t]; bi[t] = c ? atomicAdd(cur_bi + t, c) : 0; }
  for (int t = tid; t < NBU; t += 256) { int c = bu[t]; bu[t] = c ? atomicAdd(cur_bu + t, c) : 0; }
  __syncthreads();
#pragma unroll
  for (int j = 0; j < 16; ++j) {
    int idx = tid + j * 256;
    if (idx < n) {
      int s = (int)es[idx].x, d = (int)es[idx].y;
      int bI = d / Wi, bU = s / Wu;
      int pI = atomicAdd(&bi[bI], 1);
      int pU = atomicAdd(&bu[bU], 1);
      ebuf_i[pI] = ((unsigned)(d - bI * Wi) << 24) | (unsigned)s;
      ebuf_u[pU] = ((unsigned)(s - bU * Wu) << 24) | (unsigned)d;
    }
  }
}

__global__ __launch_bounds__(256) void bucket_fill2_k(
    const unsigned int* __restrict__ ebuf, const int* __restrict__ off,
    const int* __restrict__ endc, int* __restrict__ row,
    int* __restrict__ csr, int n, int W, int E) {
  int b = blockIdx.x;
  int d0 = b * W; if (d0 >= n) return;
  int cnt = n - d0; if (cnt > W) cnt = W;
  __shared__ int hist[320];
  __shared__ int cur[320];
  int tid = threadIdx.x;
  for (int t = tid; t < cnt; t += 256) hist[t] = 0;
  __syncthreads();
  int beg = off[b], e_end = endc[b];
  for (int e = beg + tid; e < e_end; e += 256)
    atomicAdd(&hist[ebuf[e] >> 24], 1);
  __syncthreads();
  if (tid < 64) {
    int lane = tid;
    int carry = beg;
    int nc = (cnt + 63) >> 6;
    for (int c = 0; c < nc; ++c) {
      int idx = (c << 6) + lane;
      int v = (idx < cnt) ? hist[idx] : 0;
      int x = v;
#pragma unroll
      for (int o = 1; o < 64; o <<= 1) { int t = __shfl_up(x, o); if (lane >= o) x += t; }
      if (idx < cnt) { int g = carry + x - v; row[d0 + idx] = g; cur[idx] = g; }
      carry += __shfl(x, 63);
    }
  }
  if (tid == 0 && d0 + cnt == n) row[n] = E;
  __syncthreads();
  for (int e = beg + tid; e < e_end; e += 256) {
    unsigned v = ebuf[e];
    int slot = atomicAdd(&cur[v >> 24], 1);
    csr[slot] = (int)(v & 0xFFFFFFu);
  }
}

// ---------------- dtype prep ----------------
__global__ void cvt_bf16_k(const float* __restrict__ in, bf16_t* __restrict__ out, int n4) {
  int i = blockIdx.x * blockDim.x + threadIdx.x;
  if (i < n4) {
    float4 v = ((const float4*)in)[i];
    ushort4 o; o.x = f2bf(v.x); o.y = f2bf(v.y); o.z = f2bf(v.z); o.w = f2bf(v.w);
    ((ushort4*)out)[i] = o;
  }
}

struct WBatch { const float* in[4]; bf16_t* out[4]; };
__global__ void twconv_batch_k(WBatch wb, int K, int N) {
  const float* __restrict__ in = wb.in[blockIdx.z];
  bf16_t* __restrict__ out = wb.out[blockIdx.z];
  __shared__ float t[32][33];
  int bx = blockIdx.x * 32, by = blockIdx.y * 32;
  int tx = threadIdx.x & 31, ty = threadIdx.x >> 5;  // 32x8
#pragma unroll
  for (int j = 0; j < 32; j += 8)
    t[ty + j][tx] = in[(size_t)(by + ty + j) * N + bx + tx];
  __syncthreads();
#pragma unroll
  for (int j = 0; j < 32; j += 8)
    out[(size_t)(bx + ty + j) * K + by + tx] = f2bf(t[tx][ty + j]);
}

// ---------------- gather-mean, D=128, 16 lanes/row, paired jobs ------------
struct GatherJob {
  const int* row; const int* csr;
  const bf16_t* X; bf16_t* agg; int n;
};

template<bool ADD>
__global__ void gather_mean16_k(GatherJob j0, GatherJob j1) {
  GatherJob j = blockIdx.y ? j1 : j0;
  int node = (int)(((long long)blockIdx.x * blockDim.x + threadIdx.x) >> 6);
  int lane = threadIdx.x & 63;
  if (node >= j.n) return;
  const int g = lane >> 4;
  const int l = lane & 15;
  int beg = j.row[node], end = j.row[node + 1];
  float acc[8] = {};
  for (int jj = beg; jj < end; jj += 64) {
    int cnt = min(64, end - jj);
    int my = (lane < cnt) ? j.csr[jj + lane] : 0;
    for (int k = 0; k < cnt; k += 4) {
      int idx = __shfl(my, k + g);
      if (k + g < cnt) {
        uint4 u = *(const uint4*)(j.X + (size_t)idx * 128 + l * 8);
        acc8(acc, u);
      }
    }
  }
#pragma unroll
  for (int m = 16; m < 64; m <<= 1)
#pragma unroll
    for (int i = 0; i < 8; ++i) acc[i] += __shfl_xor(acc[i], m);
  if (g == 0) {
    float inv = (end > beg) ? 1.0f / (float)(end - beg) : 0.0f;
    float v[8];
    if (ADD) {
      uint4 z = *(const uint4*)(j.agg + (size_t)node * 128 + l * 8);
      float zb[8]; unpack8(zb, z);
#pragma unroll
      for (int i = 0; i < 8; ++i) v[i] = acc[i] * inv + zb[i];
    } else {
#pragma unroll
      for (int i = 0; i < 8; ++i) v[i] = acc[i] * inv;
    }
    *(uint4*)(j.agg + (size_t)node * 128 + l * 8) = pack8(v);
  }
}

// ---------------- MFMA GEMM (2-phase double-buffered, paired jobs) ----------
// C = act( A1 @ W1 [+ A2 @ W2] [+ bias] ), A* bf16 [M,K] row-major,
// W*t bf16 [N,K] row-major. 128x128 tile, 4 waves, BK=32.
// Pipeline: stage(t+1) issued BEFORE ds_read/MFMA of t; one barrier per step.
struct GJob {
  int M;
  const bf16_t* A1; const bf16_t* A2;
  const bf16_t* W1t; const bf16_t* W2t;
  const float* bias;
  bf16_t* C; bf16_t* C2;
};

template<bool RELU, bool DUAL, bool BIAS, bool SPLIT>
__global__ __launch_bounds__(256) void mfma_gemm_k(GJob j0, GJob j1, int N, int K) {
  GJob j = blockIdx.z ? j1 : j0;
  const size_t row0 = (size_t)blockIdx.y * 128;
  if (row0 >= (size_t)j.M) return;           // uniform exit (other job is larger)
  const int col0 = blockIdx.x * 128;
  __shared__ __align__(16) bf16_t Als[2][128 * 32];
  __shared__ __align__(16) bf16_t Bls[2][128 * 32];
  const int tid = threadIdx.x;
  const int wave = tid >> 6, lane = tid & 63;
  const int wr = wave >> 1, wc = wave & 1;
  const int M = j.M;
  const int ksteps = K >> 5;
  const int nsteps = (DUAL ? 2 : 1) * ksteps;
  const int fbase = wave * 2048 + lane * 16;   // byte offset of this lane's 16B slot

  f32x4 acc[4][4] = {};

  auto STAGE = [&](int t, int b) {
    int s = (DUAL && t >= ksteps) ? 1 : 0;
    const bf16_t* __restrict__ Ap = s ? j.A2 : j.A1;
    const bf16_t* __restrict__ Wp = s ? j.W2t : j.W1t;
    int k0 = (t - (s ? ksteps : 0)) << 5;
#pragma unroll
    for (int seg = 0; seg < 2; ++seg) {
      const int f = fbase + seg * 1024;
      const int r = f >> 6;              // tile row/col 0..127
      const int ke = (f & 63) >> 1;      // element offset within 32-elem k-slice
      size_t ar = row0 + r; if (ar >= (size_t)M) ar = M - 1;
      __builtin_amdgcn_global_load_lds(
          (const __attribute__((address_space(1))) void*)(Ap + ar * K + k0 + ke),
          (__attribute__((address_space(3))) void*)(&Als[b][0] + (f >> 1)), 16, 0, 0);
      __builtin_amdgcn_global_load_lds(
          (const __attribute__((address_space(1))) void*)(Wp + (size_t)(col0 + r) * K + k0 + ke),
          (__attribute__((address_space(3))) void*)(&Bls[b][0] + (f >> 1)), 16, 0, 0);
    }
  };

  STAGE(0, 0);
  __syncthreads();                      // drains stage(0)
  const int aoff = (wr * 64 + (lane & 15)) * 32 + (lane >> 4) * 8;
  const int boff = (wc * 64 + (lane & 15)) * 32 + (lane >> 4) * 8;

  for (int t = 0; t < nsteps; ++t) {
    const int cur = t & 1;
    if (t + 1 < nsteps) STAGE(t + 1, cur ^ 1);   // prefetch next (issued first)
    bf16x8 af[4], bfr[4];
#pragma unroll
    for (int i = 0; i < 4; ++i) {
      af[i] = *(const bf16x8*)(&Als[cur][0] + aoff + i * 16 * 32);
      bfr[i] = *(const bf16x8*)(&Bls[cur][0] + boff + i * 16 * 32);
    }
#pragma unroll
    for (int mi = 0; mi < 4; ++mi)
#pragma unroll
      for (int ni = 0; ni < 4; ++ni)
        acc[mi][ni] = __builtin_amdgcn_mfma_f32_16x16x32_bf16(af[mi], bfr[ni], acc[mi][ni], 0, 0, 0);
    __syncthreads();                    // drains stage(t+1); orders reads vs overwrite
  }

  const int crow = wr * 64 + (lane >> 4) * 4;
  int ccol = col0 + wc * 64 + (lane & 15);
  bf16_t* Co = j.C;
  int stride = N;
  bool useBias = BIAS;
  if (SPLIT) {
    const int half = N >> 1;
    stride = half;
    if (col0 >= half) { Co = j.C2; ccol -= half; useBias = false; }
  }
#pragma unroll
  for (int mi = 0; mi < 4; ++mi) {
#pragma unroll
    for (int jj = 0; jj < 4; ++jj) {
      size_t r = row0 + crow + mi * 16 + jj;
      if (r < (size_t)M) {
#pragma unroll
        for (int ni = 0; ni < 4; ++ni) {
          float v = acc[mi][ni][jj];
          if (BIAS) { if (useBias) v += j.bias[ccol + ni * 16]; }
          if (RELU) v = fmaxf(v, 0.f);
          Co[r * stride + ccol + ni * 16] = f2bf(v);
        }
      }
    }
  }
}

// ---------------- decode: 16 lanes/label, 16B loads ----------------
__global__ void decode16_k(const int* __restrict__ ls, const int* __restrict__ ld,
                           const bf16_t* __restrict__ zu, const bf16_t* __restrict__ zi,
                           float* __restrict__ out, int L) {
  long long gid = (long long)blockIdx.x * blockDim.x + threadIdx.x;
  int w = (int)(gid >> 4);
  int l = (int)(gid & 15);
  if (w >= L) return;
  int su = ls[w], si = ld[w];
  uint4 a = *(const uint4*)(zu + (size_t)su * OO + l * 8);
  uint4 b = *(const uint4*)(zi + (size_t)si * OO + l * 8);
  const unsigned* pa = (const unsigned*)&a;
  const unsigned* pb = (const unsigned*)&b;
  float sum = 0.f;
#pragma unroll
  for (int i = 0; i < 4; ++i) {
    union { unsigned v; float f; } la, ha, lb, hb;
    la.v = pa[i] << 16;        ha.v = pa[i] & 0xffff0000u;
    lb.v = pb[i] << 16;        hb.v = pb[i] & 0xffff0000u;
    sum += la.f * lb.f + ha.f * hb.f;
  }
#pragma unroll
  for (int m = 1; m < 16; m <<= 1) sum += __shfl_xor(sum, m);
  if (l == 0) out[w] = sum;
}

// ---------------------------------------------------------------------------
extern "C" void kernel_launch(void* const* d_in, const int* in_sizes, int n_in,
                              void* d_out, int out_size, void* d_ws, size_t ws_size,
                              hipStream_t stream) {
  const float* x_user = (const float*)d_in[0];
  const float* x_item = (const float*)d_in[1];
  const int* edge_src = (const int*)d_in[2];
  const int* edge_dst = (const int*)d_in[3];
  const int* lbl_src  = (const int*)d_in[4];
  const int* lbl_dst  = (const int*)d_in[5];
  const float* wl1_ui = (const float*)d_in[6];
  const float* wr1_ui = (const float*)d_in[7];
  const float* b1_ui  = (const float*)d_in[8];
  const float* wl1_iu = (const float*)d_in[9];
  const float* wr1_iu = (const float*)d_in[10];
  const float* b1_iu  = (const float*)d_in[11];
  const float* wl2_ui = (const float*)d_in[12];
  const float* wr2_ui = (const float*)d_in[13];
  const float* b2_ui  = (const float*)d_in[14];
  const float* wl2_iu = (const float*)d_in[15];
  const float* wr2_iu = (const float*)d_in[16];
  const float* b2_iu  = (const float*)d_in[17];

  const int NU = in_sizes[0] / DD;
  const int NI = in_sizes[1] / DD;
  const int E  = in_sizes[2];
  const int L  = in_sizes[4];
  const int Wi = (NI + NBI - 1) / NBI;
  const int Wu = (NU + NBU - 1) / NBU;
  const int nEB = (E + 4095) / 4096;

  // ---- workspace layout ----
  size_t off = 0;
  auto take = [&](size_t bytes) { size_t o = off; off = (off + bytes + 255) & ~(size_t)255; return o; };
  char* base = (char*)d_ws;
  int* hist_i = (int*)(base + take(((size_t)NBI + NBU) * 4));  // zeroed together
  int* hist_u = hist_i + NBI;
  size_t zeroB = ((size_t)NBI + NBU) * 4;
  int* row_i = (int*)(base + take((size_t)(NI + 1) * 4));
  int* row_u = (int*)(base + take((size_t)(NU + 1) * 4));
  int* off_i = (int*)(base + take((size_t)NBI * 4));
  int* off_u = (int*)(base + take((size_t)NBU * 4));
  int* cur_bi = (int*)(base + take((size_t)NBI * 4));
  int* cur_bu = (int*)(base + take((size_t)NBU * 4));
  int* csr_i = (int*)(base + take((size_t)E * 4));
  int* csr_u = (int*)(base + take((size_t)E * 4));
  unsigned int* ebuf_i = (unsigned int*)(base + take((size_t)E * 4));
  unsigned int* ebuf_u = (unsigned int*)(base + take((size_t)E * 4));
  bf16_t* pool = (bf16_t*)(base + take((size_t)(NI + NU) * HH * 2));
  bf16_t* agg_i   = pool;                              // NI*DD
  bf16_t* agg_u   = agg_i + (size_t)NI * DD;           // NU*DD
  bf16_t* xb_item = agg_u + (size_t)NU * DD;           // NI*DD
  bf16_t* xb_user = xb_item + (size_t)NI * DD;         // NU*DD
  bf16_t* t_user  = pool;                              // NU*OO
  bf16_t* t_item  = t_user + (size_t)NU * OO;          // NI*OO
  bf16_t* h_item = (bf16_t*)(base + take((size_t)(NI + NU) * HH * 2));
  bf16_t* h_user = h_item + (size_t)NI * HH;
  bf16_t* z_item = (bf16_t*)(base + take((size_t)(NI + NU) * OO * 2));
  bf16_t* z_user = z_item + (size_t)NI * OO;
  bf16_t* Wt1[4];
  for (int w = 0; w < 4; ++w) Wt1[w] = (bf16_t*)(base + take((size_t)HH * DD * 2));
  bf16_t* Wcat_item = (bf16_t*)(base + take((size_t)2 * OO * HH * 2));
  bf16_t* Wcat_user = (bf16_t*)(base + take((size_t)2 * OO * HH * 2));
  size_t need = off;

  float* out = (float*)d_out;
  if (ws_size < need || Wi > 320 || Wu > 320) {
    probe_k<<<(L + 255) / 256, 256, 0, stream>>>(out, L, (float)(ws_size >> 20));
    return;
  }

  // ---- CSR build ----
  hipMemsetAsync(hist_i, 0, zeroB, stream);
  hist_k<<<nEB, 256, 0, stream>>>(edge_src, edge_dst, hist_u, hist_i, E, Wi, Wu);
  scan_small_pair_k<<<2, 512, 0, stream>>>(hist_i, off_i, cur_bi, hist_u, off_u, cur_bu);
  bucket_append_k<<<nEB, 256, 0, stream>>>(edge_src, edge_dst, E, Wi, Wu, cur_bi, cur_bu, ebuf_i, ebuf_u);
  bucket_fill2_k<<<NBI, 256, 0, stream>>>(ebuf_i, off_i, cur_bi, row_i, csr_i, NI, Wi, E);
  bucket_fill2_k<<<NBU, 256, 0, stream>>>(ebuf_u, off_u, cur_bu, row_u, csr_u, NU, Wu, E);

  // ---- dtype prep ----
  cvt_bf16_k<<<(NI * DD / 4 + 255) / 256, 256, 0, stream>>>(x_item, xb_item, NI * DD / 4);
  cvt_bf16_k<<<(NU * DD / 4 + 255) / 256, 256, 0, stream>>>(x_user, xb_user, NU * DD / 4);
  {
    WBatch w1;
    w1.in[0] = wl1_ui; w1.out[0] = Wt1[0];
    w1.in[1] = wr1_ui; w1.out[1] = Wt1[1];
    w1.in[2] = wl1_iu; w1.out[2] = Wt1[2];
    w1.in[3] = wr1_iu; w1.out[3] = Wt1[3];
    dim3 g1(HH / 32, DD / 32, 4);  // [D,H] -> [H,D]
    twconv_batch_k<<<g1, 256, 0, stream>>>(w1, DD, HH);
    WBatch w2;
    w2.in[0] = wr2_ui; w2.out[0] = Wcat_item;
    w2.in[1] = wl2_iu; w2.out[1] = Wcat_item + (size_t)OO * HH;
    w2.in[2] = wr2_iu; w2.out[2] = Wcat_user;
    w2.in[3] = wl2_ui; w2.out[3] = Wcat_user + (size_t)OO * HH;
    dim3 g2(OO / 32, HH / 32, 4);  // [H,O] -> [O,H]
    twconv_batch_k<<<g2, 256, 0, stream>>>(w2, HH, OO);
  }

  const int nbMax = ((NU > NI ? NU : NI) * 64 + 255) / 256;
  const int myMax = ((NU > NI ? NU : NI) + 127) / 128;

  // ---- layer 1: gather-mean (paired) + dual GEMM (paired) ----
  {
    GatherJob gi = { row_i, csr_i, xb_user, agg_i, NI };
    GatherJob gu = { row_u, csr_u, xb_item, agg_u, NU };
    gather_mean16_k<false><<<dim3(nbMax, 2), 256, 0, stream>>>(gi, gu);
  }
  {
    GJob ji = { NI, agg_i, xb_item, Wt1[0], Wt1[1], b1_ui, h_item, nullptr };
    GJob ju = { NU, agg_u, xb_user, Wt1[2], Wt1[3], b1_iu, h_user, nullptr };
    dim3 g(HH / 128, myMax, 2);
    mfma_gemm_k<true, true, true, false><<<g, 256, 0, stream>>>(ji, ju, HH, DD);
  }

  // ---- layer 2 (re-associated, merged split GEMMs, paired) ----
  {
    GJob ji = { NI, h_item, nullptr, Wcat_item, nullptr, b2_ui, z_item, t_item };
    GJob ju = { NU, h_user, nullptr, Wcat_user, nullptr, b2_iu, z_user, t_user };
    dim3 g(2, myMax, 2);
    mfma_gemm_k<false, false, true, true><<<g, 256, 0, stream>>>(ji, ju, 2 * OO, HH);
  }
  {
    GatherJob gi = { row_i, csr_i, t_user, z_item, NI };
    GatherJob gu = { row_u, csr_u, t_item, z_user, NU };
    gather_mean16_k<true><<<dim3(nbMax, 2), 256, 0, stream>>>(gi, gu);
  }

  // ---- decode ----
  decode16_k<<<(int)(((long long)L * 16 + 255) / 256), 256, 0, stream>>>(lbl_src, lbl_dst, z_user, z_item, out, L);
}